// Round 1
// baseline (756.117 us; speedup 1.0000x reference)
//
#include <hip/hip_runtime.h>

typedef unsigned short u16;

#define N_ 16384
#define SCALE 0.35355339059327379f   // 64^-0.25

__device__ __forceinline__ float bf2f(u16 u){
  union { unsigned int i; float f; } v; v.i = ((unsigned int)u) << 16; return v.f;
}
__device__ __forceinline__ u16 f2bf(float f){
  union { float f; unsigned int i; } v; v.f = f;
  unsigned int b = v.i;
  return (u16)((b + 0x7FFFu + ((b >> 16) & 1u)) >> 16);
}

// ---------------------------------------------------------------------------
// Kernel 1: k = scale*(Wk x + bk), v = Wv x + bv  -> bf16 buffers [B][512][N]
// Tile: 64 out-rows x 64 tokens, K=128 fully staged. LDS = 64 KiB exactly.
// wst is stored transposed [k][j] with xor-swizzled j-groups -> conflict-free
// float4 reads in the main loop.
// ---------------------------------------------------------------------------
__global__ __launch_bounds__(256)
void projkv(const float* __restrict__ x, const float* __restrict__ Wk,
            const float* __restrict__ bk, const float* __restrict__ Wv,
            const float* __restrict__ bv, u16* __restrict__ kbuf,
            u16* __restrict__ vbuf){
  __shared__ float xs[128][64];
  __shared__ float wst[128][64];
  const int tid = threadIdx.x;
  const int tb  = blockIdx.x * 64;
  const int jt  = blockIdx.y;
  const int b   = blockIdx.z;
  const bool isK = (jt < 8);
  const int j0  = (jt & 7) * 64;
  const float* W  = isK ? Wk : Wv;
  const float* bs = isK ? bk : bv;
  u16* dst = isK ? kbuf : vbuf;

  { // stage x tile [128][64]
    const int t4 = tid & 15, k0 = tid >> 4;
#pragma unroll
    for (int p = 0; p < 8; p++){
      const int row = k0 + p * 16;
      float4 v = *(const float4*)(x + (size_t)(b * 128 + row) * N_ + tb + 4 * t4);
      *(float4*)&xs[row][4 * t4] = v;
    }
  }
  { // stage W tile transposed + swizzled: wst[k][4*((j>>2)^(k&15)) + (j&3)] = W[j0+j][k]
    const int jr = tid & 7, kc = tid >> 3;  // kc 0..31
#pragma unroll
    for (int p = 0; p < 8; p++){
      const int j = jr + p * 8;
      float4 v = *(const float4*)(W + (size_t)(j0 + j) * 128 + 4 * kc);
#pragma unroll
      for (int i = 0; i < 4; i++){
        const int k = 4 * kc + i;
        wst[k][4 * ((j >> 2) ^ (k & 15)) + (j & 3)] = (&v.x)[i];
      }
    }
  }
  __syncthreads();

  const int tx = tid & 15, ty = tid >> 4;
  float acc[4][4];
#pragma unroll
  for (int a = 0; a < 4; a++)
#pragma unroll
    for (int c = 0; c < 4; c++) acc[a][c] = 0.f;

  for (int kk = 0; kk < 128; kk += 4){
#pragma unroll
    for (int i = 0; i < 4; i++){
      const int k = kk + i;
      float4 xv = *(const float4*)&xs[k][4 * tx];
      float4 wv = *(const float4*)&wst[k][4 * (ty ^ (k & 15))];
#pragma unroll
      for (int jj = 0; jj < 4; jj++){
        const float w = (&wv.x)[jj];
#pragma unroll
        for (int tt = 0; tt < 4; tt++) acc[jj][tt] += w * (&xv.x)[tt];
      }
    }
  }

  const float mul = isK ? SCALE : 1.0f;
#pragma unroll
  for (int jj = 0; jj < 4; jj++){
    const int row = j0 + 4 * ty + jj;
    const float bb = bs[row];
    ushort4 o;
    o.x = f2bf((acc[jj][0] + bb) * mul);
    o.y = f2bf((acc[jj][1] + bb) * mul);
    o.z = f2bf((acc[jj][2] + bb) * mul);
    o.w = f2bf((acc[jj][3] + bb) * mul);
    *(ushort4*)(dst + (size_t)(b * 512 + row) * N_ + tb + 4 * tx) = o;
  }
}

// ---------------------------------------------------------------------------
// Kernel 2: per-row (b, j<512) max and 1/sum(exp) over the 16384 tokens
// ---------------------------------------------------------------------------
__global__ __launch_bounds__(256)
void kstats(const u16* __restrict__ kbuf, float* __restrict__ rowmax,
            float* __restrict__ rowinv){
  const int r = blockIdx.x, tid = threadIdx.x;
  const u16* base = kbuf + (size_t)r * N_;
  __shared__ float red[256];
  float m = -1e30f;
  for (int c = tid; c < N_ / 4; c += 256){
    ushort4 u = *(const ushort4*)(base + 4 * c);
    m = fmaxf(m, fmaxf(fmaxf(bf2f(u.x), bf2f(u.y)), fmaxf(bf2f(u.z), bf2f(u.w))));
  }
  red[tid] = m; __syncthreads();
  for (int s = 128; s > 0; s >>= 1){
    if (tid < s) red[tid] = fmaxf(red[tid], red[tid + s]);
    __syncthreads();
  }
  m = red[0]; __syncthreads();
  float sum = 0.f;
  for (int c = tid; c < N_ / 4; c += 256){
    ushort4 u = *(const ushort4*)(base + 4 * c);
    sum += __expf(bf2f(u.x) - m) + __expf(bf2f(u.y) - m) +
           __expf(bf2f(u.z) - m) + __expf(bf2f(u.w) - m);
  }
  red[tid] = sum; __syncthreads();
  for (int s = 128; s > 0; s >>= 1){
    if (tid < s) red[tid] += red[tid + s];
    __syncthreads();
  }
  if (tid == 0){ rowmax[r] = m; rowinv[r] = 1.f / red[0]; }
}

// ---------------------------------------------------------------------------
// Kernel 3: ctx_raw[b,h,d,e] += sum_n exp(k[d,n]-max_d) * v[e,n]  (fp32 atomics)
// Block = (token-chunk of 512, h, b); 8 sub-tiles of 64 tokens via LDS.
// ---------------------------------------------------------------------------
__global__ __launch_bounds__(256)
void ctxacc(const u16* __restrict__ kbuf, const u16* __restrict__ vbuf,
            const float* __restrict__ rowmax, float* __restrict__ ctx){
  __shared__ float kw[64][68];
  __shared__ float vv[64][68];
  const int tid = threadIdx.x;
  const int chunk = blockIdx.x, h = blockIdx.y, b = blockIdx.z;
  const int te = tid & 15, td = tid >> 4;
  const int rbase = b * 512 + h * 64;
  float acc[4][4];
#pragma unroll
  for (int a = 0; a < 4; a++)
#pragma unroll
    for (int c = 0; c < 4; c++) acc[a][c] = 0.f;

  for (int sub = 0; sub < 8; sub++){
    const int tok0 = chunk * 512 + sub * 64;
    __syncthreads();
    {
      const int t4 = tid & 15, d0 = tid >> 4;
#pragma unroll
      for (int p = 0; p < 4; p++){
        const int d = d0 + p * 16;
        const size_t gi = (size_t)(rbase + d) * N_ + tok0 + 4 * t4;
        const float mrow = rowmax[rbase + d];
        ushort4 ku = *(const ushort4*)(kbuf + gi);
        float4 kf;
        kf.x = __expf(bf2f(ku.x) - mrow); kf.y = __expf(bf2f(ku.y) - mrow);
        kf.z = __expf(bf2f(ku.z) - mrow); kf.w = __expf(bf2f(ku.w) - mrow);
        *(float4*)&kw[d][4 * t4] = kf;
        ushort4 vu = *(const ushort4*)(vbuf + gi);
        float4 vf;
        vf.x = bf2f(vu.x); vf.y = bf2f(vu.y); vf.z = bf2f(vu.z); vf.w = bf2f(vu.w);
        *(float4*)&vv[d][4 * t4] = vf;
      }
    }
    __syncthreads();
    for (int t = 0; t < 64; t += 4){
      float4 ka[4], va[4];
#pragma unroll
      for (int dd = 0; dd < 4; dd++) ka[dd] = *(const float4*)&kw[4 * td + dd][t];
#pragma unroll
      for (int ee = 0; ee < 4; ee++) va[ee] = *(const float4*)&vv[4 * te + ee][t];
#pragma unroll
      for (int dd = 0; dd < 4; dd++)
#pragma unroll
        for (int ee = 0; ee < 4; ee++)
#pragma unroll
          for (int i = 0; i < 4; i++)
            acc[dd][ee] += (&ka[dd].x)[i] * (&va[ee].x)[i];
    }
  }
  float* cbase = ctx + (size_t)(b * 8 + h) * 64 * 64;
#pragma unroll
  for (int dd = 0; dd < 4; dd++)
#pragma unroll
    for (int ee = 0; ee < 4; ee++)
      atomicAdd(cbase + (4 * td + dd) * 64 + 4 * te + ee, acc[dd][ee]);
}

// ---------------------------------------------------------------------------
// Kernel 4: Mt[b,h,d,c] = rowinv_d * sum_e Wo[c, h*64+e] * ctx_raw[b,h,d,e]
// (folds the output projection through the tiny ctx). Output bf16.
// ---------------------------------------------------------------------------
__global__ __launch_bounds__(256)
void mker(const float* __restrict__ ctx, const float* __restrict__ Wo,
          const float* __restrict__ rowinv, u16* __restrict__ mt){
  __shared__ float ctxh[64][68];
  __shared__ float woht[64][132];
  const int tid = threadIdx.x;
  const int h = blockIdx.x, b = blockIdx.y;
  const int e4 = tid & 15, r0 = tid >> 4;
#pragma unroll
  for (int p = 0; p < 4; p++){
    const int d = r0 + p * 16;
    float4 v = *(const float4*)(ctx + ((size_t)(b * 8 + h) * 64 + d) * 64 + 4 * e4);
    *(float4*)&ctxh[d][4 * e4] = v;
  }
#pragma unroll
  for (int p = 0; p < 8; p++){
    const int c = r0 + p * 16;
    float4 v = *(const float4*)(Wo + (size_t)c * 512 + h * 64 + 4 * e4);
    woht[4 * e4 + 0][c] = v.x; woht[4 * e4 + 1][c] = v.y;
    woht[4 * e4 + 2][c] = v.z; woht[4 * e4 + 3][c] = v.w;
  }
  __syncthreads();
  const int cg = tid & 3, d = tid >> 2;
  const float inv = rowinv[b * 512 + h * 64 + d];
  float acc[32];
#pragma unroll
  for (int cc = 0; cc < 32; cc++) acc[cc] = 0.f;
  for (int e = 0; e < 64; e++){
    const float cv = ctxh[d][e];
#pragma unroll
    for (int cc = 0; cc < 32; cc++) acc[cc] += cv * woht[e][cg + 4 * cc];
  }
  u16* obase = mt + ((size_t)(b * 8 + h) * 64 + d) * 128;
#pragma unroll
  for (int cc = 0; cc < 32; cc++) obase[cg + 4 * cc] = f2bf(inv * acc[cc]);
}

// ---------------------------------------------------------------------------
// Kernel 5 (fused): q-logits = scale*(Wq x + bq), per-token softmax over d
// within each head, then out[c,t] = bo[c] + sum_{h,d} Mt[b,h,d,c] * q[d,t].
// 512 threads, 64-token tile. LDS = 64 KiB exactly; wm is dual-use
// (Wq tile / Mt tile, bf16) and its region also hosts softmax scratch.
// ---------------------------------------------------------------------------
__global__ __launch_bounds__(512)
void qfinal(const float* __restrict__ x, const float* __restrict__ Wq,
            const float* __restrict__ bq, const u16* __restrict__ mt,
            const float* __restrict__ bo, float* __restrict__ out){
  __shared__ float xs[128][64];
  __shared__ u16 wm[64 * 128];
  __shared__ float pbuf[64][64];
  float* wmf = (float*)wm;  // softmax scratch overlay (phase 2 only)

  const int tid = threadIdx.x;
  const int tb = blockIdx.x * 64;
  const int b  = blockIdx.y;

  { // stage x tile
    const int t4 = tid & 15, k0 = tid >> 4;  // k0 0..31
#pragma unroll
    for (int p = 0; p < 4; p++){
      const int row = k0 + p * 32;
      float4 v = *(const float4*)(x + (size_t)(b * 128 + row) * N_ + tb + 4 * t4);
      *(float4*)&xs[row][4 * t4] = v;
    }
  }
  const int tx = tid & 15, ty = tid >> 4;   // ty 0..31
  const int t64 = tid & 63, q8 = tid >> 6;  // softmax mapping
  float facc[4][4];
#pragma unroll
  for (int cc = 0; cc < 4; cc++){
    const float bb = bo[4 * ty + cc];
#pragma unroll
    for (int tt = 0; tt < 4; tt++) facc[cc][tt] = bb;
  }

  for (int h = 0; h < 8; h++){
    __syncthreads();
    { // stage Wq head tile -> bf16 wm[j*128+k]
      const int j = tid >> 3, kc8 = tid & 7;
#pragma unroll
      for (int p = 0; p < 4; p++){
        const int kc = kc8 + 8 * p;
        float4 v = *(const float4*)(Wq + (size_t)(h * 64 + j) * 128 + 4 * kc);
        ushort4 w;
        w.x = f2bf(v.x); w.y = f2bf(v.y); w.z = f2bf(v.z); w.w = f2bf(v.w);
        *(ushort4*)&wm[j * 128 + 4 * kc] = w;
      }
    }
    __syncthreads();
    // phase 1: logits for this head (j = 2*ty+jj, t = 4*tx+tt)
    float lacc[2][4];
#pragma unroll
    for (int jj = 0; jj < 2; jj++)
#pragma unroll
      for (int tt = 0; tt < 4; tt++) lacc[jj][tt] = 0.f;
    for (int kk = 0; kk < 128; kk += 4){
      float4 xv[4];
#pragma unroll
      for (int i = 0; i < 4; i++) xv[i] = *(const float4*)&xs[kk + i][4 * tx];
#pragma unroll
      for (int jj = 0; jj < 2; jj++){
        ushort4 wu = *(const ushort4*)&wm[(2 * ty + jj) * 128 + kk];
        float wf0 = bf2f(wu.x), wf1 = bf2f(wu.y), wf2 = bf2f(wu.z), wf3 = bf2f(wu.w);
#pragma unroll
        for (int tt = 0; tt < 4; tt++)
          lacc[jj][tt] += wf0 * (&xv[0].x)[tt] + wf1 * (&xv[1].x)[tt] +
                          wf2 * (&xv[2].x)[tt] + wf3 * (&xv[3].x)[tt];
      }
    }
#pragma unroll
    for (int jj = 0; jj < 2; jj++){
      const int j = 2 * ty + jj;
      const float bb = bq[h * 64 + j];
#pragma unroll
      for (int tt = 0; tt < 4; tt++)
        pbuf[j][4 * tx + tt] = SCALE * (lacc[jj][tt] + bb);
    }
    __syncthreads();
    // phase 2: softmax over d (64) per token column
    float* red    = wmf;        // [8][64]
    float* colmax = wmf + 512;  // [64]
    float* colinv = wmf + 576;  // [64]
    float m = -1e30f;
#pragma unroll
    for (int i = 0; i < 8; i++) m = fmaxf(m, pbuf[8 * q8 + i][t64]);
    red[q8 * 64 + t64] = m;
    __syncthreads();
    if (tid < 64){
      float mm = red[tid];
      for (int q = 1; q < 8; q++) mm = fmaxf(mm, red[q * 64 + tid]);
      colmax[tid] = mm;
    }
    __syncthreads();
    const float mm = colmax[t64];
    float s = 0.f;
#pragma unroll
    for (int i = 0; i < 8; i++){
      const float e = __expf(pbuf[8 * q8 + i][t64] - mm);
      pbuf[8 * q8 + i][t64] = e;
      s += e;
    }
    red[q8 * 64 + t64] = s;
    __syncthreads();
    if (tid < 64){
      float ss = 0.f;
      for (int q = 0; q < 8; q++) ss += red[q * 64 + tid];
      colinv[tid] = 1.f / ss;
    }
    __syncthreads();
    const float ci = colinv[t64];
#pragma unroll
    for (int i = 0; i < 8; i++) pbuf[8 * q8 + i][t64] *= ci;
    __syncthreads();
    { // stage Mt head tile (bf16) -> wm[d*128 + c]  (overwrites scratch)
      const int c4 = tid & 31, d0 = tid >> 5;
#pragma unroll
      for (int p = 0; p < 4; p++){
        const int d = d0 + p * 16;
        ushort4 v = *(const ushort4*)(mt + ((size_t)(b * 8 + h) * 64 + d) * 128 + 4 * c4);
        *(ushort4*)&wm[d * 128 + 4 * c4] = v;
      }
    }
    __syncthreads();
    // phase 3: facc[c,t] += Mt[d][c] * p[d][t]
    for (int d = 0; d < 64; d += 4){
#pragma unroll
      for (int i = 0; i < 4; i++){
        ushort4 mu = *(const ushort4*)&wm[(d + i) * 128 + 4 * ty];
        float4 pv = *(const float4*)&pbuf[d + i][4 * tx];
        float mf0 = bf2f(mu.x), mf1 = bf2f(mu.y), mf2 = bf2f(mu.z), mf3 = bf2f(mu.w);
#pragma unroll
        for (int tt = 0; tt < 4; tt++){
          const float p_ = (&pv.x)[tt];
          facc[0][tt] += mf0 * p_;
          facc[1][tt] += mf1 * p_;
          facc[2][tt] += mf2 * p_;
          facc[3][tt] += mf3 * p_;
        }
      }
    }
  }
#pragma unroll
  for (int cc = 0; cc < 4; cc++){
    float4 o;
    o.x = facc[cc][0]; o.y = facc[cc][1]; o.z = facc[cc][2]; o.w = facc[cc][3];
    *(float4*)(out + (size_t)(b * 128 + 4 * ty + cc) * N_ + tb + 4 * tx) = o;
  }
}

// ---------------------------------------------------------------------------
extern "C" void kernel_launch(void* const* d_in, const int* in_sizes, int n_in,
                              void* d_out, int out_size, void* d_ws, size_t ws_size,
                              hipStream_t stream){
  const float* x  = (const float*)d_in[0];
  const float* Wq = (const float*)d_in[1];
  const float* bq = (const float*)d_in[2];
  const float* Wk = (const float*)d_in[3];
  const float* bk = (const float*)d_in[4];
  const float* Wv = (const float*)d_in[5];
  const float* bv = (const float*)d_in[6];
  const float* Wo = (const float*)d_in[7];
  const float* bo = (const float*)d_in[8];
  float* out = (float*)d_out;

  char* ws = (char*)d_ws;
  u16* kbuf = (u16*)ws;                                   // 4*512*16384 bf16
  u16* vbuf = kbuf + (size_t)4 * 512 * 16384;             // 4*512*16384 bf16
  float* rowmax = (float*)(vbuf + (size_t)4 * 512 * 16384);
  float* rowinv = rowmax + 2048;
  float* ctx = rowinv + 2048;                             // 4*8*64*64 fp32
  u16* mt = (u16*)(ctx + 4 * 8 * 64 * 64);                // 4*8*64*128 bf16

  hipMemsetAsync(ctx, 0, (size_t)4 * 8 * 64 * 64 * sizeof(float), stream);
  projkv<<<dim3(256, 16, 4), 256, 0, stream>>>(x, Wk, bk, Wv, bv, kbuf, vbuf);
  kstats<<<2048, 256, 0, stream>>>(kbuf, rowmax, rowinv);
  ctxacc<<<dim3(32, 8, 4), 256, 0, stream>>>(kbuf, vbuf, rowmax, ctx);
  mker<<<dim3(8, 4), 256, 0, stream>>>(ctx, Wo, rowinv, mt);
  qfinal<<<dim3(256, 4), 512, 0, stream>>>(x, Wq, bq, mt, bo, out);
}

// Round 3
// 513.390 us; speedup vs baseline: 1.4728x; 1.4728x over previous
//
#include <hip/hip_runtime.h>

typedef unsigned short u16;
typedef __bf16 bf16x8 __attribute__((ext_vector_type(8)));
typedef float f32x4 __attribute__((ext_vector_type(4)));

#define N_ 16384
#define SCALE 0.35355339059327379f   // 64^-0.25

__device__ __forceinline__ float bf2f(u16 u){
  union { unsigned int i; float f; } v; v.i = ((unsigned int)u) << 16; return v.f;
}
__device__ __forceinline__ u16 f2bf(float f){
  union { float f; unsigned int i; } v; v.f = f;
  unsigned int b = v.i;
  return (u16)((b + 0x7FFFu + ((b >> 16) & 1u)) >> 16);
}

// ---------------------------------------------------------------------------
// prep: pack weights to bf16. wkvb[h][128][128]: rows 0-63 = SCALE*Wk head rows,
// 64-127 = Wv head rows. wqb[512][128] = SCALE*Wq. Biases pre-scaled to fp32.
// ---------------------------------------------------------------------------
__global__ __launch_bounds__(256) void prep(const float* __restrict__ Wq,
    const float* __restrict__ bq, const float* __restrict__ Wk,
    const float* __restrict__ bk, const float* __restrict__ Wv,
    const float* __restrict__ bv, u16* __restrict__ wkvb, u16* __restrict__ wqb,
    float* __restrict__ bkv, float* __restrict__ bqs){
  int j = blockIdx.x * 256 + threadIdx.x;  // 0..1535
  const float* src; u16* dst; float sc;
  if (j < 512){
    src = Wk + (size_t)j * 128; dst = wkvb + (size_t)((j >> 6) * 128 + (j & 63)) * 128;
    sc = SCALE; bkv[(j >> 6) * 128 + (j & 63)] = SCALE * bk[j];
  } else if (j < 1024){
    int r = j - 512;
    src = Wv + (size_t)r * 128; dst = wkvb + (size_t)((r >> 6) * 128 + 64 + (r & 63)) * 128;
    sc = 1.f; bkv[(r >> 6) * 128 + 64 + (r & 63)] = bv[r];
  } else {
    int r = j - 1024;
    src = Wq + (size_t)r * 128; dst = wqb + (size_t)r * 128;
    sc = SCALE; bqs[r] = SCALE * bq[r];
  }
#pragma unroll
  for (int p = 0; p < 32; p++){
    float4 v = *(const float4*)(src + 4 * p);
    ushort4 o;
    o.x = f2bf(sc * v.x); o.y = f2bf(sc * v.y);
    o.z = f2bf(sc * v.z); o.w = f2bf(sc * v.w);
    *(ushort4*)(dst + 4 * p) = o;
  }
}

// ---------------------------------------------------------------------------
// convx: x[b][128 k][N] fp32 -> xt[b][N t][128 k] bf16 (token-major, k contig)
// ---------------------------------------------------------------------------
__global__ __launch_bounds__(256) void convx(const float* __restrict__ x,
                                             u16* __restrict__ xt){
  __shared__ u16 lt[64][136];
  const int tid = threadIdx.x;
  const int t0 = blockIdx.x * 64;
  const int b  = blockIdx.y;
  {
    const int t4 = tid & 15, kr = tid >> 4;
#pragma unroll
    for (int p = 0; p < 8; p++){
      int k = kr + p * 16;
      float4 v = *(const float4*)(x + (size_t)(b * 128 + k) * N_ + t0 + 4 * t4);
      lt[4 * t4 + 0][k] = f2bf(v.x);
      lt[4 * t4 + 1][k] = f2bf(v.y);
      lt[4 * t4 + 2][k] = f2bf(v.z);
      lt[4 * t4 + 3][k] = f2bf(v.w);
    }
  }
  __syncthreads();
  {
    const int t = tid >> 2, kq = tid & 3;
#pragma unroll
    for (int p = 0; p < 4; p++)   // FIX R3: was p<2 with stride p*16 — wrote only
      *(uint4*)(xt + (size_t)(b * N_ + t0 + t) * 128 + kq * 32 + p * 8) =  // half of xt
          *(const uint4*)&lt[t][kq * 32 + p * 8];
  }
}

// ---------------------------------------------------------------------------
// kvctx (fused): per (512-token chunk, head, batch):
//   MFMA1: D1[j 128][t 128] = wkv_h · x^T  (4 sub-tiles of 128 tokens)
//   epilogue: +bias; rows 0-63: exp + rowsum shuffle-reduce; store ekv to LDS
//   MFMA2: ctx[d][e] += ek · ev^T  (each wave owns a 32-token quarter)
//   block LDS-reduce then one atomicAdd set into ctx. No k/v in HBM.
// LDS tiles XOR-swizzled in 16B granules: elem (row,c) at granule (c8 ^ row&15).
// ---------------------------------------------------------------------------
__global__ __launch_bounds__(256, 2) void kvctx(const u16* __restrict__ xt,
    const u16* __restrict__ wkvb, const float* __restrict__ bkv,
    float* __restrict__ rowsum, float* __restrict__ ctx){
  __shared__ u16 smX[128 * 128];   // xs tile, then ekv overlay
  __shared__ u16 smW[128 * 128];   // wkv tile; tail: red f32[64][68] overlay
  const int tid = threadIdx.x;
  const int tt = blockIdx.x;   // 0..31 token chunks of 512
  const int h  = blockIdx.y;
  const int b  = blockIdx.z;
  const int w  = tid >> 6, l = tid & 63;
  const int r15 = l & 15, q = l >> 4;
  const int wy = w >> 1, wx = w & 1;

  { // stage wkv head tile [128 j][128 k], swizzled
    const u16* src = wkvb + (size_t)h * 128 * 128;
    const int row = tid >> 1, gb = (tid & 1) * 8;
#pragma unroll
    for (int p = 0; p < 8; p++){
      int g = gb + p;
      *(uint4*)&smW[row * 128 + ((g ^ (row & 15)) * 8)] =
          *(const uint4*)&src[row * 128 + g * 8];
    }
  }

  f32x4 acc2[4][4] = {};   // D2 64x64 partials (this wave's token quarters)
  float rs[4][4] = {};     // rowsum partials (meaningful on wy==0 waves)

  for (int sub = 0; sub < 4; sub++){
    __syncthreads();
    { // stage xs[t][k] swizzled
      const u16* src = xt + (size_t)(b * N_ + tt * 512 + sub * 128) * 128;
      const int row = tid >> 1, gb = (tid & 1) * 8;
#pragma unroll
      for (int p = 0; p < 8; p++){
        int g = gb + p;
        *(uint4*)&smX[row * 128 + ((g ^ (row & 15)) * 8)] =
            *(const uint4*)&src[(size_t)row * 128 + g * 8];
      }
    }
    __syncthreads();
    // MFMA1: wave tile 64j x 64t
    f32x4 acc1[4][4] = {};
#pragma unroll
    for (int ks = 0; ks < 4; ks++){
      bf16x8 af[4], bfr[4];
#pragma unroll
      for (int mi = 0; mi < 4; mi++){
        int row = 64 * wy + 16 * mi + r15;
        af[mi] = *(const bf16x8*)&smW[row * 128 + (((4 * ks + q) ^ (row & 15)) * 8)];
      }
#pragma unroll
      for (int ni = 0; ni < 4; ni++){
        int row = 64 * wx + 16 * ni + r15;
        bfr[ni] = *(const bf16x8*)&smX[row * 128 + (((4 * ks + q) ^ (row & 15)) * 8)];
      }
#pragma unroll
      for (int mi = 0; mi < 4; mi++)
#pragma unroll
        for (int ni = 0; ni < 4; ni++)
          acc1[mi][ni] = __builtin_amdgcn_mfma_f32_16x16x32_bf16(
              af[mi], bfr[ni], acc1[mi][ni], 0, 0, 0);
    }
    __syncthreads();  // xs reads done; smX becomes ekv
    // epilogue: bias, exp for k rows, rowsum reduce, scatter ekv (swizzled)
#pragma unroll
    for (int mi = 0; mi < 4; mi++){
#pragma unroll
      for (int r = 0; r < 4; r++){
        int j = 64 * wy + 16 * mi + 4 * q + r;
        float bias = bkv[h * 128 + j];
        float vals[4];
#pragma unroll
        for (int ni = 0; ni < 4; ni++) vals[ni] = acc1[mi][ni][r] + bias;
        if (wy == 0){
          float s = 0.f;
#pragma unroll
          for (int ni = 0; ni < 4; ni++){ vals[ni] = __expf(vals[ni]); s += vals[ni]; }
          s += __shfl_xor(s, 1);  s += __shfl_xor(s, 2);
          s += __shfl_xor(s, 4);  s += __shfl_xor(s, 8);
          rs[mi][r] += s;
        }
#pragma unroll
        for (int ni = 0; ni < 4; ni++){
          int t = 64 * wx + 16 * ni + r15;
          smX[j * 128 + (((t >> 3) ^ (j & 15)) * 8) + (t & 7)] = f2bf(vals[ni]);
        }
      }
    }
    __syncthreads();
    // MFMA2: wave w consumes its 32-token quarter (granules 4w..4w+3)
    {
      bf16x8 af[4], bfr[4];
#pragma unroll
      for (int mi = 0; mi < 4; mi++){
        int d = 16 * mi + r15;
        af[mi] = *(const bf16x8*)&smX[d * 128 + (((4 * w + q) ^ (d & 15)) * 8)];
      }
#pragma unroll
      for (int ni = 0; ni < 4; ni++){
        int e = 16 * ni + r15;
        bfr[ni] = *(const bf16x8*)&smX[(64 + e) * 128 + (((4 * w + q) ^ (e & 15)) * 8)];
      }
#pragma unroll
      for (int mi = 0; mi < 4; mi++)
#pragma unroll
        for (int ni = 0; ni < 4; ni++)
          acc2[mi][ni] = __builtin_amdgcn_mfma_f32_16x16x32_bf16(
              af[mi], bfr[ni], acc2[mi][ni], 0, 0, 0);
    }
  }
  // cross-wave reduce into LDS then one global atomic pass
  __syncthreads();
  float* red = (float*)smW;   // [64][68]
  for (int i = tid; i < 64 * 68; i += 256) red[i] = 0.f;
  __syncthreads();
#pragma unroll
  for (int mi = 0; mi < 4; mi++)
#pragma unroll
    for (int ni = 0; ni < 4; ni++)
#pragma unroll
      for (int r = 0; r < 4; r++){
        int d = 16 * mi + 4 * q + r, e = 16 * ni + r15;
        atomicAdd(&red[d * 68 + e], acc2[mi][ni][r]);
      }
  __syncthreads();
  {
    float* cbase = ctx + (size_t)(b * 8 + h) * 4096;
#pragma unroll
    for (int p = 0; p < 16; p++){
      int i = tid * 16 + p;
      atomicAdd(&cbase[i], red[(i >> 6) * 68 + (i & 63)]);
    }
  }
  if (wy == 0 && r15 == 0){
    float* rbase = rowsum + (b * 8 + h) * 64;
#pragma unroll
    for (int mi = 0; mi < 4; mi++)
#pragma unroll
      for (int r = 0; r < 4; r++)
        atomicAdd(&rbase[16 * mi + 4 * q + r], rs[mi][r]);
  }
}

// ---------------------------------------------------------------------------
// mker: mt2[b][h][c][d] = (1/rowsum[d]) * sum_e Wo[c][h*64+e] * ctx[b][h][d][e]
// ---------------------------------------------------------------------------
__global__ __launch_bounds__(256) void mker(const float* __restrict__ ctx,
    const float* __restrict__ Wo, const float* __restrict__ rowsum,
    u16* __restrict__ mt2){
  __shared__ float ctxh[64][68];
  __shared__ float woht[64][132];
  const int tid = threadIdx.x;
  const int h = blockIdx.x, b = blockIdx.y;
  const int e4 = tid & 15, r0 = tid >> 4;
#pragma unroll
  for (int p = 0; p < 4; p++){
    int d = r0 + p * 16;
    float4 v = *(const float4*)(ctx + ((size_t)(b * 8 + h) * 64 + d) * 64 + 4 * e4);
    *(float4*)&ctxh[d][4 * e4] = v;
  }
#pragma unroll
  for (int p = 0; p < 8; p++){
    int c = r0 + p * 16;
    float4 v = *(const float4*)(Wo + (size_t)c * 512 + h * 64 + 4 * e4);
    woht[4 * e4 + 0][c] = v.x; woht[4 * e4 + 1][c] = v.y;
    woht[4 * e4 + 2][c] = v.z; woht[4 * e4 + 3][c] = v.w;
  }
  __syncthreads();
  const int cg = tid & 3, d = tid >> 2;
  const float inv = 1.f / rowsum[(b * 8 + h) * 64 + d];
  float acc[32];
#pragma unroll
  for (int cc = 0; cc < 32; cc++) acc[cc] = 0.f;
  for (int e = 0; e < 64; e++){
    float cv = ctxh[d][e];
#pragma unroll
    for (int cc = 0; cc < 32; cc++) acc[cc] += cv * woht[e][cg + 4 * cc];
  }
  u16* obase = mt2 + (size_t)(b * 8 + h) * 128 * 64;
#pragma unroll
  for (int cc = 0; cc < 32; cc++)
    obase[(size_t)(cg + 4 * cc) * 64 + d] = f2bf(inv * acc[cc]);
}

// ---------------------------------------------------------------------------
// qout (fused): MFMA1 q-logits -> exp -> per-token colsum (LDS) -> normalized
// pT (bf16, B-frag layout) -> MFMA2 out[c][t] += M_h · p_h; +bo at end.
// ---------------------------------------------------------------------------
__global__ __launch_bounds__(256, 2) void qout(const u16* __restrict__ xt,
    const u16* __restrict__ wqb, const float* __restrict__ bqs,
    const u16* __restrict__ mt2, const float* __restrict__ bo,
    float* __restrict__ out){
  __shared__ u16 smX[128 * 128];  // xs, persistent
  __shared__ u16 smA[128 * 64];   // wq (64x128) / ma (128x64) / colsum overlay
  __shared__ u16 smP[128 * 64];   // pT[t][d]
  float* colsum = (float*)smA;
  const int tid = threadIdx.x;
  const int tt = blockIdx.x;      // 128-token tiles
  const int b  = blockIdx.y;
  const int w = tid >> 6, l = tid & 63, r15 = l & 15, q = l >> 4;
  const int wy = w >> 1, wx = w & 1;
  const int t0 = tt * 128;

  { // stage xs[t][k] swizzled
    const u16* src = xt + (size_t)(b * N_ + t0) * 128;
    const int row = tid >> 1, gb = (tid & 1) * 8;
#pragma unroll
    for (int p = 0; p < 8; p++){
      int g = gb + p;
      *(uint4*)&smX[row * 128 + ((g ^ (row & 15)) * 8)] =
          *(const uint4*)&src[(size_t)row * 128 + g * 8];
    }
  }

  f32x4 acc3[4][4] = {};
  for (int h = 0; h < 8; h++){
    __syncthreads();
    { // stage wq head tile [64 d][128 k] swizzled (mask &15, 16 granules)
      const u16* src = wqb + (size_t)h * 64 * 128;
      const int row = tid >> 2, gb = (tid & 3) * 4;
#pragma unroll
      for (int p = 0; p < 4; p++){
        int g = gb + p;
        *(uint4*)&smA[row * 128 + ((g ^ (row & 15)) * 8)] =
            *(const uint4*)&src[row * 128 + g * 8];
      }
    }
    __syncthreads();
    // MFMA1: D1[d][t], wave tile 32d x 64t
    f32x4 acc1[2][4] = {};
#pragma unroll
    for (int ks = 0; ks < 4; ks++){
      bf16x8 af[2], bfr[4];
#pragma unroll
      for (int mi = 0; mi < 2; mi++){
        int row = 32 * wy + 16 * mi + r15;
        af[mi] = *(const bf16x8*)&smA[row * 128 + (((4 * ks + q) ^ (row & 15)) * 8)];
      }
#pragma unroll
      for (int ni = 0; ni < 4; ni++){
        int row = 64 * wx + 16 * ni + r15;
        bfr[ni] = *(const bf16x8*)&smX[row * 128 + (((4 * ks + q) ^ (row & 15)) * 8)];
      }
#pragma unroll
      for (int mi = 0; mi < 2; mi++)
#pragma unroll
        for (int ni = 0; ni < 4; ni++)
          acc1[mi][ni] = __builtin_amdgcn_mfma_f32_16x16x32_bf16(
              af[mi], bfr[ni], acc1[mi][ni], 0, 0, 0);
    }
    __syncthreads();  // wq reads done; front of smA becomes colsum
    if (tid < 128) colsum[tid] = 0.f;
    float ev[2][4][4];
#pragma unroll
    for (int mi = 0; mi < 2; mi++)
#pragma unroll
      for (int r = 0; r < 4; r++){
        int d = 32 * wy + 16 * mi + 4 * q + r;
        float bias = bqs[h * 64 + d];
#pragma unroll
        for (int ni = 0; ni < 4; ni++)
          ev[mi][ni][r] = __expf(acc1[mi][ni][r] + bias);
      }
    __syncthreads();
#pragma unroll
    for (int ni = 0; ni < 4; ni++){
      float s = 0.f;
#pragma unroll
      for (int mi = 0; mi < 2; mi++)
#pragma unroll
        for (int r = 0; r < 4; r++) s += ev[mi][ni][r];
      s += __shfl_xor(s, 16); s += __shfl_xor(s, 32);
      if (q == 0) atomicAdd(&colsum[64 * wx + 16 * ni + r15], s);
    }
    __syncthreads();
    // normalized pT[t][d] bf16, swizzled (mask &7, 8 granules)
#pragma unroll
    for (int ni = 0; ni < 4; ni++){
      int t = 64 * wx + 16 * ni + r15;
      float ci = 1.f / colsum[t];
#pragma unroll
      for (int mi = 0; mi < 2; mi++)
#pragma unroll
        for (int r = 0; r < 4; r++){
          int d = 32 * wy + 16 * mi + 4 * q + r;
          smP[t * 64 + (((d >> 3) ^ (t & 7)) * 8) + (d & 7)] = f2bf(ev[mi][ni][r] * ci);
        }
    }
    __syncthreads();
    { // stage ma[128 c][64 d] swizzled (overwrites smA incl. colsum)
      const u16* src = mt2 + (size_t)(b * 8 + h) * 128 * 64;
      const int row = tid >> 1, gb = (tid & 1) * 4;
#pragma unroll
      for (int p = 0; p < 4; p++){
        int g = gb + p;
        *(uint4*)&smA[row * 64 + ((g ^ (row & 7)) * 8)] =
            *(const uint4*)&src[row * 64 + g * 8];
      }
    }
    __syncthreads();
    // MFMA2: wave tile 64c x 64t, K=64
#pragma unroll
    for (int ks = 0; ks < 2; ks++){
      bf16x8 af[4], bfr[4];
#pragma unroll
      for (int mi = 0; mi < 4; mi++){
        int c = 64 * wy + 16 * mi + r15;
        af[mi] = *(const bf16x8*)&smA[c * 64 + (((4 * ks + q) ^ (c & 7)) * 8)];
      }
#pragma unroll
      for (int ni = 0; ni < 4; ni++){
        int t = 64 * wx + 16 * ni + r15;
        bfr[ni] = *(const bf16x8*)&smP[t * 64 + (((4 * ks + q) ^ (t & 7)) * 8)];
      }
#pragma unroll
      for (int mi = 0; mi < 4; mi++)
#pragma unroll
        for (int ni = 0; ni < 4; ni++)
          acc3[mi][ni] = __builtin_amdgcn_mfma_f32_16x16x32_bf16(
              af[mi], bfr[ni], acc3[mi][ni], 0, 0, 0);
    }
  }
#pragma unroll
  for (int mi = 0; mi < 4; mi++)
#pragma unroll
    for (int r = 0; r < 4; r++){
      int c = 64 * wy + 16 * mi + 4 * q + r;
      float bb = bo[c];
#pragma unroll
      for (int ni = 0; ni < 4; ni++){
        int t = 64 * wx + 16 * ni + r15;
        out[(size_t)(b * 128 + c) * N_ + t0 + t] = acc3[mi][ni][r] + bb;
      }
    }
}

// ---------------------------------------------------------------------------
extern "C" void kernel_launch(void* const* d_in, const int* in_sizes, int n_in,
                              void* d_out, int out_size, void* d_ws, size_t ws_size,
                              hipStream_t stream){
  const float* x  = (const float*)d_in[0];
  const float* Wq = (const float*)d_in[1];
  const float* bq = (const float*)d_in[2];
  const float* Wk = (const float*)d_in[3];
  const float* bk = (const float*)d_in[4];
  const float* Wv = (const float*)d_in[5];
  const float* bv = (const float*)d_in[6];
  const float* Wo = (const float*)d_in[7];
  const float* bo = (const float*)d_in[8];
  float* out = (float*)d_out;

  char* ws = (char*)d_ws;
  u16*   xt     = (u16*)ws;                         // 4*16384*128 bf16 = 16 MiB
  u16*   wkvb   = (u16*)(ws + 16777216);            // 8*128*128
  u16*   wqb    = (u16*)(ws + 17039360);            // 512*128
  float* bkv    = (float*)(ws + 17170432);          // 1024
  float* bqs    = (float*)(ws + 17174528);          // 512
  float* rowsum = (float*)(ws + 17176576);          // 2048 (zeroed)
  float* ctx    = (float*)(ws + 17184768);          // 4*8*64*64 (zeroed)
  u16*   mt2    = (u16*)(ws + 17709056);            // 4*8*128*64

  hipMemsetAsync(ws + 17176576, 0, 8192 + 524288, stream);  // rowsum+ctx
  prep <<<6, 256, 0, stream>>>(Wq, bq, Wk, bk, Wv, bv, wkvb, wqb, bkv, bqs);
  convx<<<dim3(256, 4), 256, 0, stream>>>(x, xt);
  kvctx<<<dim3(32, 8, 4), 256, 0, stream>>>(xt, wkvb, bkv, rowsum, ctx);
  mker <<<dim3(8, 4), 256, 0, stream>>>(ctx, Wo, rowsum, mt2);
  qout <<<dim3(128, 4), 256, 0, stream>>>(xt, wqb, bqs, mt2, bo, out);
}

// Round 4
// 316.671 us; speedup vs baseline: 2.3877x; 1.6212x over previous
//
#include <hip/hip_runtime.h>

typedef unsigned short u16;
typedef __bf16 bf16x8 __attribute__((ext_vector_type(8)));
typedef float f32x4 __attribute__((ext_vector_type(4)));

#define N_ 16384
#define SCALE 0.35355339059327379f   // 64^-0.25

__device__ __forceinline__ float bf2f(u16 u){
  union { unsigned int i; float f; } v; v.i = ((unsigned int)u) << 16; return v.f;
}
__device__ __forceinline__ u16 f2bf(float f){
  union { float f; unsigned int i; } v; v.f = f;
  unsigned int b = v.i;
  return (u16)((b + 0x7FFFu + ((b >> 16) & 1u)) >> 16);
}

// ---------------------------------------------------------------------------
// prep: pack weights to bf16. wkvb[h][128][128]: rows 0-63 = SCALE*Wk head rows,
// 64-127 = Wv head rows. wqb[512][128] = SCALE*Wq. Biases pre-scaled to fp32.
// ---------------------------------------------------------------------------
__global__ __launch_bounds__(256) void prep(const float* __restrict__ Wq,
    const float* __restrict__ bq, const float* __restrict__ Wk,
    const float* __restrict__ bk, const float* __restrict__ Wv,
    const float* __restrict__ bv, u16* __restrict__ wkvb, u16* __restrict__ wqb,
    float* __restrict__ bkv, float* __restrict__ bqs){
  int j = blockIdx.x * 256 + threadIdx.x;  // 0..1535
  const float* src; u16* dst; float sc;
  if (j < 512){
    src = Wk + (size_t)j * 128; dst = wkvb + (size_t)((j >> 6) * 128 + (j & 63)) * 128;
    sc = SCALE; bkv[(j >> 6) * 128 + (j & 63)] = SCALE * bk[j];
  } else if (j < 1024){
    int r = j - 512;
    src = Wv + (size_t)r * 128; dst = wkvb + (size_t)((r >> 6) * 128 + 64 + (r & 63)) * 128;
    sc = 1.f; bkv[(r >> 6) * 128 + 64 + (r & 63)] = bv[r];
  } else {
    int r = j - 1024;
    src = Wq + (size_t)r * 128; dst = wqb + (size_t)r * 128;
    sc = SCALE; bqs[r] = SCALE * bq[r];
  }
#pragma unroll
  for (int p = 0; p < 32; p++){
    float4 v = *(const float4*)(src + 4 * p);
    ushort4 o;
    o.x = f2bf(sc * v.x); o.y = f2bf(sc * v.y);
    o.z = f2bf(sc * v.z); o.w = f2bf(sc * v.w);
    *(ushort4*)(dst + 4 * p) = o;
  }
}

// ---------------------------------------------------------------------------
// convx: x[b][128 k][N] fp32 -> xt[b][N t][128 k] bf16 (token-major, k contig)
// ---------------------------------------------------------------------------
__global__ __launch_bounds__(256) void convx(const float* __restrict__ x,
                                             u16* __restrict__ xt){
  __shared__ u16 lt[64][136];
  const int tid = threadIdx.x;
  const int t0 = blockIdx.x * 64;
  const int b  = blockIdx.y;
  {
    const int t4 = tid & 15, kr = tid >> 4;
#pragma unroll
    for (int p = 0; p < 8; p++){
      int k = kr + p * 16;
      float4 v = *(const float4*)(x + (size_t)(b * 128 + k) * N_ + t0 + 4 * t4);
      lt[4 * t4 + 0][k] = f2bf(v.x);
      lt[4 * t4 + 1][k] = f2bf(v.y);
      lt[4 * t4 + 2][k] = f2bf(v.z);
      lt[4 * t4 + 3][k] = f2bf(v.w);
    }
  }
  __syncthreads();
  {
    const int t = tid >> 2, kq = tid & 3;
#pragma unroll
    for (int p = 0; p < 4; p++)
      *(uint4*)(xt + (size_t)(b * N_ + t0 + t) * 128 + kq * 32 + p * 8) =
          *(const uint4*)&lt[t][kq * 32 + p * 8];
  }
}

// ---------------------------------------------------------------------------
// kvctx (fused): per (512-token chunk, head, batch):
//   MFMA1: D1[j 128][t 128] = wkv_h · x^T  (4 sub-tiles of 128 tokens)
//   epilogue: +bias; rows 0-63: exp + rowsum shuffle-reduce; store ekv to LDS
//   MFMA2: ctx[d][e] += ek · ev^T  (each wave owns a 32-token quarter)
//   R4: NO global atomics — per-wave partials block-reduced through LDS
//   (smX/smW reused, dead after last MFMA2) and streamed to pctx[bh][tt][4096];
//   rowsum partials to prs[bh][tt][128]. ctxred sums them.
// ---------------------------------------------------------------------------
__global__ __launch_bounds__(256, 2) void kvctx(const u16* __restrict__ xt,
    const u16* __restrict__ wkvb, const float* __restrict__ bkv,
    float* __restrict__ pctx, float* __restrict__ prs){
  __shared__ u16 smX[128 * 128];   // xs tile -> ekv overlay -> partials 0/1
  __shared__ u16 smW[128 * 128];   // wkv tile -> partials 2/3
  const int tid = threadIdx.x;
  const int tt = blockIdx.x;   // 0..31 token chunks of 512
  const int h  = blockIdx.y;
  const int b  = blockIdx.z;
  const int w  = tid >> 6, l = tid & 63;
  const int r15 = l & 15, q = l >> 4;
  const int wy = w >> 1, wx = w & 1;

  { // stage wkv head tile [128 j][128 k], swizzled
    const u16* src = wkvb + (size_t)h * 128 * 128;
    const int row = tid >> 1, gb = (tid & 1) * 8;
#pragma unroll
    for (int p = 0; p < 8; p++){
      int g = gb + p;
      *(uint4*)&smW[row * 128 + ((g ^ (row & 15)) * 8)] =
          *(const uint4*)&src[row * 128 + g * 8];
    }
  }

  f32x4 acc2[4][4] = {};   // D2 64x64 partials (this wave's token quarters)
  float rs[4][4] = {};     // rowsum partials (meaningful on wy==0 waves)

  for (int sub = 0; sub < 4; sub++){
    __syncthreads();
    { // stage xs[t][k] swizzled
      const u16* src = xt + (size_t)(b * N_ + tt * 512 + sub * 128) * 128;
      const int row = tid >> 1, gb = (tid & 1) * 8;
#pragma unroll
      for (int p = 0; p < 8; p++){
        int g = gb + p;
        *(uint4*)&smX[row * 128 + ((g ^ (row & 15)) * 8)] =
            *(const uint4*)&src[(size_t)row * 128 + g * 8];
      }
    }
    __syncthreads();
    // MFMA1: wave tile 64j x 64t
    f32x4 acc1[4][4] = {};
#pragma unroll
    for (int ks = 0; ks < 4; ks++){
      bf16x8 af[4], bfr[4];
#pragma unroll
      for (int mi = 0; mi < 4; mi++){
        int row = 64 * wy + 16 * mi + r15;
        af[mi] = *(const bf16x8*)&smW[row * 128 + (((4 * ks + q) ^ (row & 15)) * 8)];
      }
#pragma unroll
      for (int ni = 0; ni < 4; ni++){
        int row = 64 * wx + 16 * ni + r15;
        bfr[ni] = *(const bf16x8*)&smX[row * 128 + (((4 * ks + q) ^ (row & 15)) * 8)];
      }
#pragma unroll
      for (int mi = 0; mi < 4; mi++)
#pragma unroll
        for (int ni = 0; ni < 4; ni++)
          acc1[mi][ni] = __builtin_amdgcn_mfma_f32_16x16x32_bf16(
              af[mi], bfr[ni], acc1[mi][ni], 0, 0, 0);
    }
    __syncthreads();  // xs reads done; smX becomes ekv
    // epilogue: bias, exp for k rows, rowsum reduce, scatter ekv (swizzled)
#pragma unroll
    for (int mi = 0; mi < 4; mi++){
#pragma unroll
      for (int r = 0; r < 4; r++){
        int j = 64 * wy + 16 * mi + 4 * q + r;
        float bias = bkv[h * 128 + j];
        float vals[4];
#pragma unroll
        for (int ni = 0; ni < 4; ni++) vals[ni] = acc1[mi][ni][r] + bias;
        if (wy == 0){
          float s = 0.f;
#pragma unroll
          for (int ni = 0; ni < 4; ni++){ vals[ni] = __expf(vals[ni]); s += vals[ni]; }
          s += __shfl_xor(s, 1);  s += __shfl_xor(s, 2);
          s += __shfl_xor(s, 4);  s += __shfl_xor(s, 8);
          rs[mi][r] += s;
        }
#pragma unroll
        for (int ni = 0; ni < 4; ni++){
          int t = 64 * wx + 16 * ni + r15;
          smX[j * 128 + (((t >> 3) ^ (j & 15)) * 8) + (t & 7)] = f2bf(vals[ni]);
        }
      }
    }
    __syncthreads();
    // MFMA2: wave w consumes its 32-token quarter (granules 4w..4w+3)
    {
      bf16x8 af[4], bfr[4];
#pragma unroll
      for (int mi = 0; mi < 4; mi++){
        int d = 16 * mi + r15;
        af[mi] = *(const bf16x8*)&smX[d * 128 + (((4 * w + q) ^ (d & 15)) * 8)];
      }
#pragma unroll
      for (int ni = 0; ni < 4; ni++){
        int e = 16 * ni + r15;
        bfr[ni] = *(const bf16x8*)&smX[(64 + e) * 128 + (((4 * w + q) ^ (e & 15)) * 8)];
      }
#pragma unroll
      for (int mi = 0; mi < 4; mi++)
#pragma unroll
        for (int ni = 0; ni < 4; ni++)
          acc2[mi][ni] = __builtin_amdgcn_mfma_f32_16x16x32_bf16(
              af[mi], bfr[ni], acc2[mi][ni], 0, 0, 0);
    }
  }
  // ---- R4 ending: LDS block-reduce + streaming stores, zero atomics ----
  __syncthreads();   // all waves done with smX/smW contents
  {
    float* wreg = (w < 2 ? (float*)smX : (float*)smW) + (size_t)(w & 1) * 4096;
#pragma unroll
    for (int mi = 0; mi < 4; mi++)
#pragma unroll
      for (int ni = 0; ni < 4; ni++)
#pragma unroll
        for (int r = 0; r < 4; r++){
          int d = 16 * mi + 4 * q + r, e = 16 * ni + r15;
          wreg[d * 64 + e] = acc2[mi][ni][r];
        }
  }
  if (wy == 0 && r15 == 0){   // rowsum partials (group-reduced, lane q holds 16)
    float* rb = prs + ((size_t)((b * 8 + h) * 32 + tt)) * 128 + wx * 64;
#pragma unroll
    for (int mi = 0; mi < 4; mi++)
#pragma unroll
      for (int r = 0; r < 4; r++)
        rb[16 * mi + 4 * q + r] = rs[mi][r];
  }
  __syncthreads();
  {
    const float* p0 = (const float*)smX;
    const float* p1 = (const float*)smW;
    float* dst = pctx + ((size_t)((b * 8 + h) * 32 + tt)) * 4096 + tid * 16;
#pragma unroll
    for (int i = 0; i < 4; i++){
      int o = tid * 16 + 4 * i;
      float4 a = *(const float4*)(p0 + o);
      float4 c = *(const float4*)(p0 + 4096 + o);
      float4 d = *(const float4*)(p1 + o);
      float4 e = *(const float4*)(p1 + 4096 + o);
      float4 s;
      s.x = a.x + c.x + d.x + e.x;
      s.y = a.y + c.y + d.y + e.y;
      s.z = a.z + c.z + d.z + e.z;
      s.w = a.w + c.w + d.w + e.w;
      *(float4*)(dst + 4 * i) = s;
    }
  }
}

// ---------------------------------------------------------------------------
// ctxred: ctx[bh][4096] = sum_tt pctx[bh][tt][4096];
//         rowsum[bh][64] = sum_tt (prs[bh][tt][d] + prs[bh][tt][64+d])
// ---------------------------------------------------------------------------
__global__ __launch_bounds__(256) void ctxred(const float* __restrict__ pctx,
    const float* __restrict__ prs, float* __restrict__ ctx,
    float* __restrict__ rowsum){
  const int bh = blockIdx.x, tid = threadIdx.x;
  const float* base = pctx + (size_t)bh * 32 * 4096 + tid * 16;
  float4 acc[4] = {};
  for (int t = 0; t < 32; t++){
#pragma unroll
    for (int i = 0; i < 4; i++){
      float4 v = *(const float4*)(base + (size_t)t * 4096 + 4 * i);
      acc[i].x += v.x; acc[i].y += v.y; acc[i].z += v.z; acc[i].w += v.w;
    }
  }
  float* cdst = ctx + (size_t)bh * 4096 + tid * 16;
#pragma unroll
  for (int i = 0; i < 4; i++) *(float4*)(cdst + 4 * i) = acc[i];
  if (tid < 64){
    const float* rb = prs + (size_t)bh * 32 * 128 + tid;
    float s = 0.f;
    for (int t = 0; t < 32; t++) s += rb[t * 128] + rb[t * 128 + 64];
    rowsum[bh * 64 + tid] = s;
  }
}

// ---------------------------------------------------------------------------
// mker: mt2[b][h][c][d] = (1/rowsum[d]) * sum_e Wo[c][h*64+e] * ctx[b][h][d][e]
// ---------------------------------------------------------------------------
__global__ __launch_bounds__(256) void mker(const float* __restrict__ ctx,
    const float* __restrict__ Wo, const float* __restrict__ rowsum,
    u16* __restrict__ mt2){
  __shared__ float ctxh[64][68];
  __shared__ float woht[64][132];
  const int tid = threadIdx.x;
  const int h = blockIdx.x, b = blockIdx.y;
  const int e4 = tid & 15, r0 = tid >> 4;
#pragma unroll
  for (int p = 0; p < 4; p++){
    int d = r0 + p * 16;
    float4 v = *(const float4*)(ctx + ((size_t)(b * 8 + h) * 64 + d) * 64 + 4 * e4);
    *(float4*)&ctxh[d][4 * e4] = v;
  }
#pragma unroll
  for (int p = 0; p < 8; p++){
    int c = r0 + p * 16;
    float4 v = *(const float4*)(Wo + (size_t)c * 512 + h * 64 + 4 * e4);
    woht[4 * e4 + 0][c] = v.x; woht[4 * e4 + 1][c] = v.y;
    woht[4 * e4 + 2][c] = v.z; woht[4 * e4 + 3][c] = v.w;
  }
  __syncthreads();
  const int cg = tid & 3, d = tid >> 2;
  const float inv = 1.f / rowsum[(b * 8 + h) * 64 + d];
  float acc[32];
#pragma unroll
  for (int cc = 0; cc < 32; cc++) acc[cc] = 0.f;
  for (int e = 0; e < 64; e++){
    float cv = ctxh[d][e];
#pragma unroll
    for (int cc = 0; cc < 32; cc++) acc[cc] += cv * woht[e][cg + 4 * cc];
  }
  u16* obase = mt2 + (size_t)(b * 8 + h) * 128 * 64;
#pragma unroll
  for (int cc = 0; cc < 32; cc++)
    obase[(size_t)(cg + 4 * cc) * 64 + d] = f2bf(inv * acc[cc]);
}

// ---------------------------------------------------------------------------
// qout (fused): MFMA1 q-logits -> exp -> per-token colsum (LDS) -> normalized
// pT (bf16, B-frag layout) -> MFMA2 out[c][t] += M_h · p_h; +bo at end.
// ---------------------------------------------------------------------------
__global__ __launch_bounds__(256, 2) void qout(const u16* __restrict__ xt,
    const u16* __restrict__ wqb, const float* __restrict__ bqs,
    const u16* __restrict__ mt2, const float* __restrict__ bo,
    float* __restrict__ out){
  __shared__ u16 smX[128 * 128];  // xs, persistent
  __shared__ u16 smA[128 * 64];   // wq (64x128) / ma (128x64) / colsum overlay
  __shared__ u16 smP[128 * 64];   // pT[t][d]
  float* colsum = (float*)smA;
  const int tid = threadIdx.x;
  const int tt = blockIdx.x;      // 128-token tiles
  const int b  = blockIdx.y;
  const int w = tid >> 6, l = tid & 63, r15 = l & 15, q = l >> 4;
  const int wy = w >> 1, wx = w & 1;
  const int t0 = tt * 128;

  { // stage xs[t][k] swizzled
    const u16* src = xt + (size_t)(b * N_ + t0) * 128;
    const int row = tid >> 1, gb = (tid & 1) * 8;
#pragma unroll
    for (int p = 0; p < 8; p++){
      int g = gb + p;
      *(uint4*)&smX[row * 128 + ((g ^ (row & 15)) * 8)] =
          *(const uint4*)&src[(size_t)row * 128 + g * 8];
    }
  }

  f32x4 acc3[4][4] = {};
  for (int h = 0; h < 8; h++){
    __syncthreads();
    { // stage wq head tile [64 d][128 k] swizzled (mask &15, 16 granules)
      const u16* src = wqb + (size_t)h * 64 * 128;
      const int row = tid >> 2, gb = (tid & 3) * 4;
#pragma unroll
      for (int p = 0; p < 4; p++){
        int g = gb + p;
        *(uint4*)&smA[row * 128 + ((g ^ (row & 15)) * 8)] =
            *(const uint4*)&src[row * 128 + g * 8];
      }
    }
    __syncthreads();
    // MFMA1: D1[d][t], wave tile 32d x 64t
    f32x4 acc1[2][4] = {};
#pragma unroll
    for (int ks = 0; ks < 4; ks++){
      bf16x8 af[2], bfr[4];
#pragma unroll
      for (int mi = 0; mi < 2; mi++){
        int row = 32 * wy + 16 * mi + r15;
        af[mi] = *(const bf16x8*)&smA[row * 128 + (((4 * ks + q) ^ (row & 15)) * 8)];
      }
#pragma unroll
      for (int ni = 0; ni < 4; ni++){
        int row = 64 * wx + 16 * ni + r15;
        bfr[ni] = *(const bf16x8*)&smX[row * 128 + (((4 * ks + q) ^ (row & 15)) * 8)];
      }
#pragma unroll
      for (int mi = 0; mi < 2; mi++)
#pragma unroll
        for (int ni = 0; ni < 4; ni++)
          acc1[mi][ni] = __builtin_amdgcn_mfma_f32_16x16x32_bf16(
              af[mi], bfr[ni], acc1[mi][ni], 0, 0, 0);
    }
    __syncthreads();  // wq reads done; front of smA becomes colsum
    if (tid < 128) colsum[tid] = 0.f;
    float ev[2][4][4];
#pragma unroll
    for (int mi = 0; mi < 2; mi++)
#pragma unroll
      for (int r = 0; r < 4; r++){
        int d = 32 * wy + 16 * mi + 4 * q + r;
        float bias = bqs[h * 64 + d];
#pragma unroll
        for (int ni = 0; ni < 4; ni++)
          ev[mi][ni][r] = __expf(acc1[mi][ni][r] + bias);
      }
    __syncthreads();
#pragma unroll
    for (int ni = 0; ni < 4; ni++){
      float s = 0.f;
#pragma unroll
      for (int mi = 0; mi < 2; mi++)
#pragma unroll
        for (int r = 0; r < 4; r++) s += ev[mi][ni][r];
      s += __shfl_xor(s, 16); s += __shfl_xor(s, 32);
      if (q == 0) atomicAdd(&colsum[64 * wx + 16 * ni + r15], s);
    }
    __syncthreads();
    // normalized pT[t][d] bf16, swizzled (mask &7, 8 granules)
#pragma unroll
    for (int ni = 0; ni < 4; ni++){
      int t = 64 * wx + 16 * ni + r15;
      float ci = 1.f / colsum[t];
#pragma unroll
      for (int mi = 0; mi < 2; mi++)
#pragma unroll
        for (int r = 0; r < 4; r++){
          int d = 32 * wy + 16 * mi + 4 * q + r;
          smP[t * 64 + (((d >> 3) ^ (t & 7)) * 8) + (d & 7)] = f2bf(ev[mi][ni][r] * ci);
        }
    }
    __syncthreads();
    { // stage ma[128 c][64 d] swizzled (overwrites smA incl. colsum)
      const u16* src = mt2 + (size_t)(b * 8 + h) * 128 * 64;
      const int row = tid >> 1, gb = (tid & 1) * 4;
#pragma unroll
      for (int p = 0; p < 4; p++){
        int g = gb + p;
        *(uint4*)&smA[row * 64 + ((g ^ (row & 7)) * 8)] =
            *(const uint4*)&src[row * 64 + g * 8];
      }
    }
    __syncthreads();
    // MFMA2: wave tile 64c x 64t, K=64
#pragma unroll
    for (int ks = 0; ks < 2; ks++){
      bf16x8 af[4], bfr[4];
#pragma unroll
      for (int mi = 0; mi < 4; mi++){
        int c = 64 * wy + 16 * mi + r15;
        af[mi] = *(const bf16x8*)&smA[c * 64 + (((4 * ks + q) ^ (c & 7)) * 8)];
      }
#pragma unroll
      for (int ni = 0; ni < 4; ni++){
        int t = 64 * wx + 16 * ni + r15;
        bfr[ni] = *(const bf16x8*)&smP[t * 64 + (((4 * ks + q) ^ (t & 7)) * 8)];
      }
#pragma unroll
      for (int mi = 0; mi < 4; mi++)
#pragma unroll
        for (int ni = 0; ni < 4; ni++)
          acc3[mi][ni] = __builtin_amdgcn_mfma_f32_16x16x32_bf16(
              af[mi], bfr[ni], acc3[mi][ni], 0, 0, 0);
    }
  }
#pragma unroll
  for (int mi = 0; mi < 4; mi++)
#pragma unroll
    for (int r = 0; r < 4; r++){
      int c = 64 * wy + 16 * mi + 4 * q + r;
      float bb = bo[c];
#pragma unroll
      for (int ni = 0; ni < 4; ni++){
        int t = 64 * wx + 16 * ni + r15;
        out[(size_t)(b * 128 + c) * N_ + t0 + t] = acc3[mi][ni][r] + bb;
      }
    }
}

// ---------------------------------------------------------------------------
extern "C" void kernel_launch(void* const* d_in, const int* in_sizes, int n_in,
                              void* d_out, int out_size, void* d_ws, size_t ws_size,
                              hipStream_t stream){
  const float* x  = (const float*)d_in[0];
  const float* Wq = (const float*)d_in[1];
  const float* bq = (const float*)d_in[2];
  const float* Wk = (const float*)d_in[3];
  const float* bk = (const float*)d_in[4];
  const float* Wv = (const float*)d_in[5];
  const float* bv = (const float*)d_in[6];
  const float* Wo = (const float*)d_in[7];
  const float* bo = (const float*)d_in[8];
  float* out = (float*)d_out;

  char* ws = (char*)d_ws;
  u16*   xt     = (u16*)ws;                         // 16 MiB
  u16*   wkvb   = (u16*)(ws + 16777216);            // 256 KiB
  u16*   wqb    = (u16*)(ws + 17039360);            // 128 KiB
  float* bkv    = (float*)(ws + 17170432);          // 4 KiB
  float* bqs    = (float*)(ws + 17174528);          // 2 KiB
  float* rowsum = (float*)(ws + 17176576);          // 8 KiB
  float* ctx    = (float*)(ws + 17184768);          // 512 KiB
  u16*   mt2    = (u16*)(ws + 17709056);            // 128 KiB
  float* pctx   = (float*)(ws + 17840128);          // 32*32*4096*4 = 16 MiB
  float* prs    = (float*)(ws + 34617344);          // 32*32*128*4 = 512 KiB

  prep <<<6, 256, 0, stream>>>(Wq, bq, Wk, bk, Wv, bv, wkvb, wqb, bkv, bqs);
  convx<<<dim3(256, 4), 256, 0, stream>>>(x, xt);
  kvctx<<<dim3(32, 8, 4), 256, 0, stream>>>(xt, wkvb, bkv, pctx, prs);
  ctxred<<<32, 256, 0, stream>>>(pctx, prs, ctx, rowsum);
  mker <<<dim3(8, 4), 256, 0, stream>>>(ctx, Wo, rowsum, mt2);
  qout <<<dim3(128, 4), 256, 0, stream>>>(xt, wqb, bqs, mt2, bo, out);
}

// Round 5
// 278.878 us; speedup vs baseline: 2.7113x; 1.1355x over previous
//
#include <hip/hip_runtime.h>

typedef unsigned short u16;
typedef __bf16 bf16x8 __attribute__((ext_vector_type(8)));
typedef float f32x4 __attribute__((ext_vector_type(4)));

#define N_ 16384
#define SCALE 0.35355339059327379f   // 64^-0.25

__device__ __forceinline__ u16 f2bf(float f){
  union { float f; unsigned int i; } v; v.f = f;
  unsigned int b = v.i;
  return (u16)((b + 0x7FFFu + ((b >> 16) & 1u)) >> 16);
}

// ---------------------------------------------------------------------------
// prep: pack weights into MFMA A-fragment order (16x16x32 layout:
// A[m][k], lane = (m&15) | (((k>>3)&3)<<4), elem i = k&7).
// wkvf frag id f = ((h*4+jq)*2+mi)*4+ks : row j=32jq+16mi+(l&15) of [SCALE*Wk_h; Wv_h]
// wqf  frag id f = ((h*2+wy)*2+mi)*4+ks : row d=32wy+16mi+(l&15) of SCALE*Wq_h
// ---------------------------------------------------------------------------
__global__ __launch_bounds__(256) void prep(const float* __restrict__ Wq,
    const float* __restrict__ bq, const float* __restrict__ Wk,
    const float* __restrict__ bk, const float* __restrict__ Wv,
    const float* __restrict__ bv, u16* __restrict__ wkvf, u16* __restrict__ wqf,
    float* __restrict__ bkv, float* __restrict__ bqs){
  const int T = blockIdx.x * 256 + threadIdx.x;   // 0..24575
  if (T < 1024){
    int jj = T & 127, h = T >> 7;
    bkv[T] = (jj < 64) ? SCALE * bk[h * 64 + jj] : bv[h * 64 + jj - 64];
  } else if (T < 1536){
    bqs[T - 1024] = SCALE * bq[T - 1024];
  }
  const float* src; float sc; u16* dst;
  if (T < 16384){
    int l = T & 63, f = T >> 6;
    int ks = f & 3, mi = (f >> 2) & 1, jq = (f >> 3) & 3, h = f >> 5;
    int jj = 32 * jq + 16 * mi + (l & 15);
    int k0 = ks * 32 + (l >> 4) * 8;
    if (jj < 64){ src = Wk + (size_t)(h * 64 + jj) * 128 + k0; sc = SCALE; }
    else        { src = Wv + (size_t)(h * 64 + jj - 64) * 128 + k0; sc = 1.f; }
    dst = wkvf + (size_t)f * 512 + l * 8;
  } else {
    int T2 = T - 16384;
    int l = T2 & 63, f = T2 >> 6;
    int ks = f & 3, mi = (f >> 2) & 1, wy = (f >> 3) & 1, h = f >> 4;
    int d = 32 * wy + 16 * mi + (l & 15);
    int k0 = ks * 32 + (l >> 4) * 8;
    src = Wq + (size_t)(h * 64 + d) * 128 + k0; sc = SCALE;
    dst = wqf + (size_t)f * 512 + l * 8;
  }
  float4 a = *(const float4*)src, c = *(const float4*)(src + 4);
  ushort4 o0, o1;
  o0.x = f2bf(sc * a.x); o0.y = f2bf(sc * a.y); o0.z = f2bf(sc * a.z); o0.w = f2bf(sc * a.w);
  o1.x = f2bf(sc * c.x); o1.y = f2bf(sc * c.y); o1.z = f2bf(sc * c.z); o1.w = f2bf(sc * c.w);
  *(ushort4*)dst = o0; *(ushort4*)(dst + 4) = o1;
}

// ---------------------------------------------------------------------------
// convx: x[b][128 k][N] fp32 -> xt[b][N t][128 k] bf16 (token-major, k contig)
// ---------------------------------------------------------------------------
__global__ __launch_bounds__(256) void convx(const float* __restrict__ x,
                                             u16* __restrict__ xt){
  __shared__ u16 lt[64][136];
  const int tid = threadIdx.x;
  const int t0 = blockIdx.x * 64;
  const int b  = blockIdx.y;
  {
    const int t4 = tid & 15, kr = tid >> 4;
#pragma unroll
    for (int p = 0; p < 8; p++){
      int k = kr + p * 16;
      float4 v = *(const float4*)(x + (size_t)(b * 128 + k) * N_ + t0 + 4 * t4);
      lt[4 * t4 + 0][k] = f2bf(v.x);
      lt[4 * t4 + 1][k] = f2bf(v.y);
      lt[4 * t4 + 2][k] = f2bf(v.z);
      lt[4 * t4 + 3][k] = f2bf(v.w);
    }
  }
  __syncthreads();
  {
    const int t = tid >> 2, kq = tid & 3;
#pragma unroll
    for (int p = 0; p < 4; p++)
      *(uint4*)(xt + (size_t)(b * N_ + t0 + t) * 128 + kq * 32 + p * 8) =
          *(const uint4*)&lt[t][kq * 32 + p * 8];
  }
}

// ---------------------------------------------------------------------------
// kvctx R5: 4 waves (jq = j-quarter for MFMA1; (dh,eh) ctx quadrant for MFMA2).
// 64-token subs, xs double-buffer (2x16 KiB), weights in registers, ekv
// overlays current buffer, ctx quadrant accumulated in registers across subs.
// ---------------------------------------------------------------------------
__global__ __launch_bounds__(256, 3) void kvctx(const u16* __restrict__ xt,
    const u16* __restrict__ wkvf, const float* __restrict__ bkv,
    float* __restrict__ pctx, float* __restrict__ prs){
  __shared__ u16 sx[2][64 * 128];   // xs[t][k] swizzled; ekv overlay [j][t]
  const int tid = threadIdx.x;
  const int tchunk = blockIdx.x, h = blockIdx.y, b = blockIdx.z;
  const int jq = tid >> 6, l = tid & 63, r15 = l & 15, q = l >> 4;
  const int dh = jq & 1, eh = jq >> 1;
  const int srow = tid >> 2, sg = tid & 3;   // staging: row, granule-quad

  bf16x8 wf[2][4];
  {
    const u16* base = wkvf + (size_t)((h * 4 + jq) * 8) * 512 + l * 8;
#pragma unroll
    for (int mi = 0; mi < 2; mi++)
#pragma unroll
      for (int ks = 0; ks < 4; ks++)
        wf[mi][ks] = *(const bf16x8*)(base + (size_t)(mi * 4 + ks) * 512);
  }
  float barr[2][4];
#pragma unroll
  for (int mi = 0; mi < 2; mi++)
#pragma unroll
    for (int r = 0; r < 4; r++)
      barr[mi][r] = bkv[h * 128 + 32 * jq + 16 * mi + 4 * q + r];

  const size_t tok0 = (size_t)b * N_ + tchunk * 512;

  { // prologue: stage sub 0 into sx[0]
    const u16* src = xt + (tok0 + srow) * 128 + sg * 32;
    uint4 v[4];
#pragma unroll
    for (int p = 0; p < 4; p++) v[p] = *(const uint4*)(src + p * 8);
#pragma unroll
    for (int p = 0; p < 4; p++){
      int g = sg * 4 + p;
      *(uint4*)&sx[0][srow * 128 + ((g ^ (srow & 15)) * 8)] = v[p];
    }
  }
  __syncthreads();

  f32x4 acc2[2][2] = {};
  float rs[2][4] = {};

  for (int sub = 0; sub < 8; sub++){
    const int cur = sub & 1;
    uint4 pf[4];
    if (sub < 7){
      const u16* src = xt + (tok0 + (sub + 1) * 64 + srow) * 128 + sg * 32;
#pragma unroll
      for (int p = 0; p < 4; p++) pf[p] = *(const uint4*)(src + p * 8);
    }
    // MFMA1: this wave's 32 j-rows x all 64 tokens, K=128
    f32x4 acc1[2][4] = {};
#pragma unroll
    for (int ks = 0; ks < 4; ks++){
      bf16x8 bfr[4];
#pragma unroll
      for (int ni = 0; ni < 4; ni++){
        int t = 16 * ni + r15, g = ks * 4 + q;
        bfr[ni] = *(const bf16x8*)&sx[cur][t * 128 + ((g ^ (t & 15)) * 8)];
      }
#pragma unroll
      for (int mi = 0; mi < 2; mi++)
#pragma unroll
        for (int ni = 0; ni < 4; ni++)
          acc1[mi][ni] = __builtin_amdgcn_mfma_f32_16x16x32_bf16(
              wf[mi][ks], bfr[ni], acc1[mi][ni], 0, 0, 0);
    }
    if (sub < 7){
#pragma unroll
      for (int p = 0; p < 4; p++){
        int g = sg * 4 + p;
        *(uint4*)&sx[cur ^ 1][srow * 128 + ((g ^ (srow & 15)) * 8)] = pf[p];
      }
    }
    __syncthreads();   // MFMA1 reads done; xs(sub+1) staged
    // epilogue -> ekv overlay [j 0..127][t 0..63], granule swizzle ^(j&7)
    u16* ekv = sx[cur];
#pragma unroll
    for (int mi = 0; mi < 2; mi++){
#pragma unroll
      for (int r = 0; r < 4; r++){
        int j = 32 * jq + 16 * mi + 4 * q + r;
        float vals[4];
#pragma unroll
        for (int ni = 0; ni < 4; ni++) vals[ni] = acc1[mi][ni][r] + barr[mi][r];
        if (jq < 2){
          float s = 0.f;
#pragma unroll
          for (int ni = 0; ni < 4; ni++){ vals[ni] = __expf(vals[ni]); s += vals[ni]; }
          s += __shfl_xor(s, 1); s += __shfl_xor(s, 2);
          s += __shfl_xor(s, 4); s += __shfl_xor(s, 8);
          rs[mi][r] += s;
        }
#pragma unroll
        for (int ni = 0; ni < 4; ni++){
          int t = 16 * ni + r15;
          ekv[j * 64 + (((t >> 3) ^ (j & 7)) * 8) + (t & 7)] = f2bf(vals[ni]);
        }
      }
    }
    __syncthreads();   // ekv ready
    // MFMA2: quadrant (dh, eh) of ctx, K=64 tokens via 2 chunks of 32
#pragma unroll
    for (int ks2 = 0; ks2 < 2; ks2++){
      bf16x8 af[2], bfr2[2];
#pragma unroll
      for (int mi2 = 0; mi2 < 2; mi2++){
        int j = 32 * dh + 16 * mi2 + r15, g = ks2 * 4 + q;
        af[mi2] = *(const bf16x8*)&ekv[j * 64 + ((g ^ (j & 7)) * 8)];
      }
#pragma unroll
      for (int ni2 = 0; ni2 < 2; ni2++){
        int j = 64 + 32 * eh + 16 * ni2 + r15, g = ks2 * 4 + q;
        bfr2[ni2] = *(const bf16x8*)&ekv[j * 64 + ((g ^ (j & 7)) * 8)];
      }
#pragma unroll
      for (int mi2 = 0; mi2 < 2; mi2++)
#pragma unroll
        for (int ni2 = 0; ni2 < 2; ni2++)
          acc2[mi2][ni2] = __builtin_amdgcn_mfma_f32_16x16x32_bf16(
              af[mi2], bfr2[ni2], acc2[mi2][ni2], 0, 0, 0);
    }
    __syncthreads();   // MFMA2 reads done (buffer reusable)
  }
  // write this wave's 32x32 ctx quadrant straight from registers
  {
    float* dst = pctx + ((size_t)((b * 8 + h) * 32 + tchunk)) * 4096;
#pragma unroll
    for (int mi2 = 0; mi2 < 2; mi2++)
#pragma unroll
      for (int ni2 = 0; ni2 < 2; ni2++)
#pragma unroll
        for (int r = 0; r < 4; r++){
          int d = 32 * dh + 16 * mi2 + 4 * q + r, e = 32 * eh + 16 * ni2 + r15;
          dst[d * 64 + e] = acc2[mi2][ni2][r];
        }
  }
  if (jq < 2 && r15 == 0){
    float* rb = prs + ((size_t)((b * 8 + h) * 32 + tchunk)) * 64;
#pragma unroll
    for (int mi = 0; mi < 2; mi++)
#pragma unroll
      for (int r = 0; r < 4; r++)
        rb[32 * jq + 16 * mi + 4 * q + r] = rs[mi][r];
  }
}

// ---------------------------------------------------------------------------
// ctxred: ctx[bh][4096] = sum_tt pctx[bh][tt][4096]; rowsum from prs
// ---------------------------------------------------------------------------
__global__ __launch_bounds__(256) void ctxred(const float* __restrict__ pctx,
    const float* __restrict__ prs, float* __restrict__ ctx,
    float* __restrict__ rowsum){
  const int bh = blockIdx.x, tid = threadIdx.x;
  const float* base = pctx + (size_t)bh * 32 * 4096 + tid * 16;
  float4 acc[4] = {};
  for (int t = 0; t < 32; t++){
#pragma unroll
    for (int i = 0; i < 4; i++){
      float4 v = *(const float4*)(base + (size_t)t * 4096 + 4 * i);
      acc[i].x += v.x; acc[i].y += v.y; acc[i].z += v.z; acc[i].w += v.w;
    }
  }
  float* cdst = ctx + (size_t)bh * 4096 + tid * 16;
#pragma unroll
  for (int i = 0; i < 4; i++) *(float4*)(cdst + 4 * i) = acc[i];
  if (tid < 64){
    const float* rb = prs + (size_t)bh * 32 * 64 + tid;
    float s = 0.f;
    for (int t = 0; t < 32; t++) s += rb[t * 64];
    rowsum[bh * 64 + tid] = s;
  }
}

// ---------------------------------------------------------------------------
// mker: M[c][d] = (1/rowsum[d]) * sum_e Wo[c][h*64+e] * ctx[b][h][d][e],
// output in MFMA A-fragment order (frag f = ((bh*2+wy)*4+mi)*2+ks).
// ---------------------------------------------------------------------------
__global__ __launch_bounds__(256) void mker(const float* __restrict__ ctx,
    const float* __restrict__ Wo, const float* __restrict__ rowsum,
    u16* __restrict__ mtf){
  __shared__ float ctxh[64][68];
  __shared__ float woht[64][132];
  const int tid = threadIdx.x;
  const int h = blockIdx.x, b = blockIdx.y;
  const int bh = b * 8 + h;
  const int e4 = tid & 15, r0 = tid >> 4;
#pragma unroll
  for (int p = 0; p < 4; p++){
    int d = r0 + p * 16;
    float4 v = *(const float4*)(ctx + ((size_t)bh * 64 + d) * 64 + 4 * e4);
    *(float4*)&ctxh[d][4 * e4] = v;
  }
#pragma unroll
  for (int p = 0; p < 8; p++){
    int c = r0 + p * 16;
    float4 v = *(const float4*)(Wo + (size_t)c * 512 + h * 64 + 4 * e4);
    woht[4 * e4 + 0][c] = v.x; woht[4 * e4 + 1][c] = v.y;
    woht[4 * e4 + 2][c] = v.z; woht[4 * e4 + 3][c] = v.w;
  }
  __syncthreads();
  const int cg = tid & 3, d = tid >> 2;
  const float inv = 1.f / rowsum[bh * 64 + d];
  float acc[32];
#pragma unroll
  for (int cc = 0; cc < 32; cc++) acc[cc] = 0.f;
  for (int e = 0; e < 64; e++){
    float cv = ctxh[d][e];
#pragma unroll
    for (int cc = 0; cc < 32; cc++) acc[cc] += cv * woht[e][cg + 4 * cc];
  }
  const int ks = d >> 5, lq = ((d >> 3) & 3) << 4, i = d & 7;
#pragma unroll
  for (int cc = 0; cc < 32; cc++){
    int c = cg + 4 * cc;
    int f = ((bh * 2 + (c >> 6)) * 4 + ((c >> 4) & 3)) * 2 + ks;
    mtf[(size_t)f * 512 + ((c & 15) | lq) * 8 + i] = f2bf(inv * acc[cc]);
  }
}

// ---------------------------------------------------------------------------
// qout R5: weights/M as register frags; LDS = xs(32K) + smP(16K) + colsum;
// 3 barriers per head.
// ---------------------------------------------------------------------------
__global__ __launch_bounds__(256, 3) void qout(const u16* __restrict__ xt,
    const u16* __restrict__ wqf, const float* __restrict__ bqs,
    const u16* __restrict__ mtf, const float* __restrict__ bo,
    float* __restrict__ out){
  __shared__ u16 smX[128 * 128];  // xs[t][k] swizzled, persistent
  __shared__ u16 smP[128 * 64];   // pT[t][d] swizzled
  __shared__ float colsum[128];
  const int tid = threadIdx.x;
  const int tt = blockIdx.x;      // 128-token tiles
  const int b  = blockIdx.y;
  const int bh0 = b * 8;
  const int w = tid >> 6, l = tid & 63, r15 = l & 15, q = l >> 4;
  const int wy = w >> 1, wx = w & 1;
  const int t0 = tt * 128;

  { // stage xs[t][k] swizzled
    const u16* src = xt + (size_t)(b * N_ + t0) * 128;
    const int row = tid >> 1, gb = (tid & 1) * 8;
#pragma unroll
    for (int p = 0; p < 8; p++){
      int g = gb + p;
      *(uint4*)&smX[row * 128 + ((g ^ (row & 15)) * 8)] =
          *(const uint4*)&src[(size_t)row * 128 + g * 8];
    }
  }
  if (tid < 128) colsum[tid] = 0.f;
  __syncthreads();

  f32x4 acc3[4][4] = {};
  for (int h = 0; h < 8; h++){
    // wq frags for this wave's 32 d-rows
    bf16x8 wq[2][4];
    {
      const u16* base = wqf + (size_t)((h * 2 + wy) * 8) * 512 + l * 8;
#pragma unroll
      for (int mi = 0; mi < 2; mi++)
#pragma unroll
        for (int ks = 0; ks < 4; ks++)
          wq[mi][ks] = *(const bf16x8*)(base + (size_t)(mi * 4 + ks) * 512);
    }
    // MFMA1: D1[d 32 rows][t 64 cols], K=128
    f32x4 acc1[2][4] = {};
#pragma unroll
    for (int ks = 0; ks < 4; ks++){
      bf16x8 bfr[4];
#pragma unroll
      for (int ni = 0; ni < 4; ni++){
        int row = 64 * wx + 16 * ni + r15, g = ks * 4 + q;
        bfr[ni] = *(const bf16x8*)&smX[row * 128 + ((g ^ (row & 15)) * 8)];
      }
#pragma unroll
      for (int mi = 0; mi < 2; mi++)
#pragma unroll
        for (int ni = 0; ni < 4; ni++)
          acc1[mi][ni] = __builtin_amdgcn_mfma_f32_16x16x32_bf16(
              wq[mi][ks], bfr[ni], acc1[mi][ni], 0, 0, 0);
    }
    float ev[2][4][4];
#pragma unroll
    for (int mi = 0; mi < 2; mi++)
#pragma unroll
      for (int r = 0; r < 4; r++){
        int d = 32 * wy + 16 * mi + 4 * q + r;
        float bias = bqs[h * 64 + d];
#pragma unroll
        for (int ni = 0; ni < 4; ni++)
          ev[mi][ni][r] = __expf(acc1[mi][ni][r] + bias);
      }
#pragma unroll
    for (int ni = 0; ni < 4; ni++){
      float s = 0.f;
#pragma unroll
      for (int mi = 0; mi < 2; mi++)
#pragma unroll
        for (int r = 0; r < 4; r++) s += ev[mi][ni][r];
      s += __shfl_xor(s, 16); s += __shfl_xor(s, 32);
      if (q == 0) atomicAdd(&colsum[64 * wx + 16 * ni + r15], s);
    }
    __syncthreads();   // colsum complete
    // M frags for this wave's 64 c-rows
    bf16x8 maf[4][2];
    {
      const u16* base = mtf + (size_t)(((bh0 + h) * 2 + wy) * 8) * 512 + l * 8;
#pragma unroll
      for (int mi = 0; mi < 4; mi++)
#pragma unroll
        for (int ks = 0; ks < 2; ks++)
          maf[mi][ks] = *(const bf16x8*)(base + (size_t)(mi * 2 + ks) * 512);
    }
#pragma unroll
    for (int ni = 0; ni < 4; ni++){
      int t = 64 * wx + 16 * ni + r15;
      float ci = 1.f / colsum[t];
#pragma unroll
      for (int mi = 0; mi < 2; mi++)
#pragma unroll
        for (int r = 0; r < 4; r++){
          int d = 32 * wy + 16 * mi + 4 * q + r;
          smP[t * 64 + (((d >> 3) ^ (t & 7)) * 8) + (d & 7)] = f2bf(ev[mi][ni][r] * ci);
        }
    }
    __syncthreads();   // smP ready
    // MFMA2: out tile 64c x 64t, K=64
#pragma unroll
    for (int ks = 0; ks < 2; ks++){
      bf16x8 bfr[4];
#pragma unroll
      for (int ni = 0; ni < 4; ni++){
        int t = 64 * wx + 16 * ni + r15;
        bfr[ni] = *(const bf16x8*)&smP[t * 64 + (((4 * ks + q) ^ (t & 7)) * 8)];
      }
#pragma unroll
      for (int mi = 0; mi < 4; mi++)
#pragma unroll
        for (int ni = 0; ni < 4; ni++)
          acc3[mi][ni] = __builtin_amdgcn_mfma_f32_16x16x32_bf16(
              maf[mi][ks], bfr[ni], acc3[mi][ni], 0, 0, 0);
    }
    if (tid < 128) colsum[tid] = 0.f;  // reset for next head (read phase done)
    __syncthreads();   // smP/colsum reusable
  }
#pragma unroll
  for (int mi = 0; mi < 4; mi++)
#pragma unroll
    for (int r = 0; r < 4; r++){
      int c = 64 * wy + 16 * mi + 4 * q + r;
      float bb = bo[c];
#pragma unroll
      for (int ni = 0; ni < 4; ni++){
        int t = 64 * wx + 16 * ni + r15;
        out[(size_t)(b * 128 + c) * N_ + t0 + t] = acc3[mi][ni][r] + bb;
      }
    }
}

// ---------------------------------------------------------------------------
extern "C" void kernel_launch(void* const* d_in, const int* in_sizes, int n_in,
                              void* d_out, int out_size, void* d_ws, size_t ws_size,
                              hipStream_t stream){
  const float* x  = (const float*)d_in[0];
  const float* Wq = (const float*)d_in[1];
  const float* bq = (const float*)d_in[2];
  const float* Wk = (const float*)d_in[3];
  const float* bk = (const float*)d_in[4];
  const float* Wv = (const float*)d_in[5];
  const float* bv = (const float*)d_in[6];
  const float* Wo = (const float*)d_in[7];
  const float* bo = (const float*)d_in[8];
  float* out = (float*)d_out;

  char* ws = (char*)d_ws;
  u16*   xt     = (u16*)ws;                         // 16 MiB
  u16*   wkvf   = (u16*)(ws + 16777216);            // 256 KiB
  u16*   wqf    = (u16*)(ws + 17039360);            // 128 KiB
  u16*   mtf    = (u16*)(ws + 17170432);            // 512 KiB
  float* bkv    = (float*)(ws + 17694720);          // 4 KiB
  float* bqs    = (float*)(ws + 17698816);          // 2 KiB
  float* rowsum = (float*)(ws + 17700864);          // 8 KiB
  float* ctx    = (float*)(ws + 17709056);          // 512 KiB
  float* pctx   = (float*)(ws + 18233344);          // 16 MiB
  float* prs    = (float*)(ws + 35010560);          // 512 KiB

  prep <<<96, 256, 0, stream>>>(Wq, bq, Wk, bk, Wv, bv, wkvf, wqf, bkv, bqs);
  convx<<<dim3(256, 4), 256, 0, stream>>>(x, xt);
  kvctx<<<dim3(32, 8, 4), 256, 0, stream>>>(xt, wkvf, bkv, pctx, prs);
  ctxred<<<32, 256, 0, stream>>>(pctx, prs, ctx, rowsum);
  mker <<<dim3(8, 4), 256, 0, stream>>>(ctx, Wo, rowsum, mtf);
  qout <<<dim3(128, 4), 256, 0, stream>>>(xt, wqf, bqs, mtf, bo, out);
}

// Round 6
// 247.113 us; speedup vs baseline: 3.0598x; 1.1285x over previous
//
#include <hip/hip_runtime.h>

typedef unsigned short u16;
typedef __bf16 bf16x8 __attribute__((ext_vector_type(8)));
typedef float f32x4 __attribute__((ext_vector_type(4)));

#define N_ 16384
#define SCALE 0.35355339059327379f   // 64^-0.25

__device__ __forceinline__ u16 f2bf(float f){
  union { float f; unsigned int i; } v; v.f = f;
  unsigned int b = v.i;
  return (u16)((b + 0x7FFFu + ((b >> 16) & 1u)) >> 16);
}

// ---------------------------------------------------------------------------
// prep: pack weights into MFMA A-fragment order (16x16x32 layout:
// A[m][k], lane = (m&15) | (((k>>3)&3)<<4), elem i = k&7).
// wkvf frag id f = ((h*4+jq)*2+mi)*4+ks : row j=32jq+16mi+(l&15) of [SCALE*Wk_h; Wv_h]
// wqf  frag id f = ((h*2+wy)*2+mi)*4+ks : row d=32wy+16mi+(l&15) of SCALE*Wq_h
// ---------------------------------------------------------------------------
__global__ __launch_bounds__(256) void prep(const float* __restrict__ Wq,
    const float* __restrict__ bq, const float* __restrict__ Wk,
    const float* __restrict__ bk, const float* __restrict__ Wv,
    const float* __restrict__ bv, u16* __restrict__ wkvf, u16* __restrict__ wqf,
    float* __restrict__ bkv, float* __restrict__ bqs){
  const int T = blockIdx.x * 256 + threadIdx.x;   // 0..24575
  if (T < 1024){
    int jj = T & 127, h = T >> 7;
    bkv[T] = (jj < 64) ? SCALE * bk[h * 64 + jj] : bv[h * 64 + jj - 64];
  } else if (T < 1536){
    bqs[T - 1024] = SCALE * bq[T - 1024];
  }
  const float* src; float sc; u16* dst;
  if (T < 16384){
    int l = T & 63, f = T >> 6;
    int ks = f & 3, mi = (f >> 2) & 1, jq = (f >> 3) & 3, h = f >> 5;
    int jj = 32 * jq + 16 * mi + (l & 15);
    int k0 = ks * 32 + (l >> 4) * 8;
    if (jj < 64){ src = Wk + (size_t)(h * 64 + jj) * 128 + k0; sc = SCALE; }
    else        { src = Wv + (size_t)(h * 64 + jj - 64) * 128 + k0; sc = 1.f; }
    dst = wkvf + (size_t)f * 512 + l * 8;
  } else {
    int T2 = T - 16384;
    int l = T2 & 63, f = T2 >> 6;
    int ks = f & 3, mi = (f >> 2) & 1, wy = (f >> 3) & 1, h = f >> 4;
    int d = 32 * wy + 16 * mi + (l & 15);
    int k0 = ks * 32 + (l >> 4) * 8;
    src = Wq + (size_t)(h * 64 + d) * 128 + k0; sc = SCALE;
    dst = wqf + (size_t)f * 512 + l * 8;
  }
  float4 a = *(const float4*)src, c = *(const float4*)(src + 4);
  ushort4 o0, o1;
  o0.x = f2bf(sc * a.x); o0.y = f2bf(sc * a.y); o0.z = f2bf(sc * a.z); o0.w = f2bf(sc * a.w);
  o1.x = f2bf(sc * c.x); o1.y = f2bf(sc * c.y); o1.z = f2bf(sc * c.z); o1.w = f2bf(sc * c.w);
  *(ushort4*)dst = o0; *(ushort4*)(dst + 4) = o1;
}

// ---------------------------------------------------------------------------
// convx: x[b][128 k][N] fp32 -> xt[b][N t][128 k] bf16 (token-major, k contig)
// ---------------------------------------------------------------------------
__global__ __launch_bounds__(256) void convx(const float* __restrict__ x,
                                             u16* __restrict__ xt){
  __shared__ u16 lt[64][136];
  const int tid = threadIdx.x;
  const int t0 = blockIdx.x * 64;
  const int b  = blockIdx.y;
  {
    const int t4 = tid & 15, kr = tid >> 4;
#pragma unroll
    for (int p = 0; p < 8; p++){
      int k = kr + p * 16;
      float4 v = *(const float4*)(x + (size_t)(b * 128 + k) * N_ + t0 + 4 * t4);
      lt[4 * t4 + 0][k] = f2bf(v.x);
      lt[4 * t4 + 1][k] = f2bf(v.y);
      lt[4 * t4 + 2][k] = f2bf(v.z);
      lt[4 * t4 + 3][k] = f2bf(v.w);
    }
  }
  __syncthreads();
  {
    const int t = tid >> 2, kq = tid & 3;
#pragma unroll
    for (int p = 0; p < 4; p++)
      *(uint4*)(xt + (size_t)(b * N_ + t0 + t) * 128 + kq * 32 + p * 8) =
          *(const uint4*)&lt[t][kq * 32 + p * 8];
  }
}

// ---------------------------------------------------------------------------
// kvctx R6: block = (512-tok chunk, head-pair, b). 4 subs of 128 tokens staged
// once each and reused by 2 heads. Per head: MFMA1 [128j x 128t] (wave = 32 j
// rows), epilogue->ekv[128j][128t], MFMA2 quadrant accumulated in regs across
// subs+heads. 2 barriers/head/sub. ctx partials flushed via LDS as contiguous
// 16 KiB streams (no partial-line scatter).
// ---------------------------------------------------------------------------
__global__ __launch_bounds__(256, 2) void kvctx(const u16* __restrict__ xt,
    const u16* __restrict__ wkvf, const float* __restrict__ bkv,
    float* __restrict__ pctx, float* __restrict__ prs){
  __shared__ u16 sx[128 * 128];     // x tile [t][k] swizzled ^(t&15)
  __shared__ u16 sekv[128 * 128];   // ekv [j][t] swizzled ^(j&15); f32 flush overlay
  const int tid = threadIdx.x;
  const int chunk = blockIdx.x, hp = blockIdx.y, b = blockIdx.z;
  const int jq = tid >> 6, l = tid & 63, r15 = l & 15, q = l >> 4;
  const int dh = jq & 1, eh = jq >> 1;
  const int srow = tid >> 1, sg = (tid & 1) * 8;

  // preload weight frags + biases for both heads of the pair
  bf16x8 wf[2][2][4];
  float barr[2][2][4];
#pragma unroll
  for (int hh = 0; hh < 2; hh++){
    const int h = hp * 2 + hh;
    const u16* base = wkvf + (size_t)((h * 4 + jq) * 8) * 512 + l * 8;
#pragma unroll
    for (int mi = 0; mi < 2; mi++){
#pragma unroll
      for (int ks = 0; ks < 4; ks++)
        wf[hh][mi][ks] = *(const bf16x8*)(base + (size_t)(mi * 4 + ks) * 512);
#pragma unroll
      for (int r = 0; r < 4; r++)
        barr[hh][mi][r] = bkv[h * 128 + 32 * jq + 16 * mi + 4 * q + r];
    }
  }

  const size_t tok0 = (size_t)b * N_ + chunk * 512;
  f32x4 acc2[2][2][2] = {};   // [head][mi2][ni2] 32x32 ctx quadrant
  float rs[2][2][4] = {};     // rowsum partials (jq<2 waves)

  for (int sub = 0; sub < 4; sub++){
    { // stage 128-token x tile (coalesced 128 B/thread)
      const u16* src = xt + (tok0 + sub * 128 + srow) * 128;
      uint4 v[8];
#pragma unroll
      for (int p = 0; p < 8; p++) v[p] = *(const uint4*)(src + (sg + p) * 8);
#pragma unroll
      for (int p = 0; p < 8; p++){
        int g = sg + p;
        *(uint4*)&sx[srow * 128 + ((g ^ (srow & 15)) * 8)] = v[p];
      }
    }
    __syncthreads();
#pragma unroll
    for (int hh = 0; hh < 2; hh++){
      // MFMA1 in two 64-token halves (keeps acc1/ev register footprint low)
#pragma unroll
      for (int th = 0; th < 2; th++){
        f32x4 acc1[2][4] = {};
#pragma unroll
        for (int ks = 0; ks < 4; ks++){
          bf16x8 bfr[4];
#pragma unroll
          for (int ni = 0; ni < 4; ni++){
            int t = th * 64 + 16 * ni + r15, g = ks * 4 + q;
            bfr[ni] = *(const bf16x8*)&sx[t * 128 + ((g ^ (t & 15)) * 8)];
          }
#pragma unroll
          for (int mi = 0; mi < 2; mi++)
#pragma unroll
            for (int ni = 0; ni < 4; ni++)
              acc1[mi][ni] = __builtin_amdgcn_mfma_f32_16x16x32_bf16(
                  wf[hh][mi][ks], bfr[ni], acc1[mi][ni], 0, 0, 0);
        }
        // epilogue for this half -> ekv
#pragma unroll
        for (int mi = 0; mi < 2; mi++){
#pragma unroll
          for (int r = 0; r < 4; r++){
            int j = 32 * jq + 16 * mi + 4 * q + r;
            float vals[4];
#pragma unroll
            for (int ni = 0; ni < 4; ni++) vals[ni] = acc1[mi][ni][r] + barr[hh][mi][r];
            if (jq < 2){
              float s = 0.f;
#pragma unroll
              for (int ni = 0; ni < 4; ni++){ vals[ni] = __expf(vals[ni]); s += vals[ni]; }
              s += __shfl_xor(s, 1); s += __shfl_xor(s, 2);
              s += __shfl_xor(s, 4); s += __shfl_xor(s, 8);
              rs[hh][mi][r] += s;
            }
#pragma unroll
            for (int ni = 0; ni < 4; ni++){
              int t = th * 64 + 16 * ni + r15;
              sekv[j * 128 + (((t >> 3) ^ (j & 15)) * 8) + (t & 7)] = f2bf(vals[ni]);
            }
          }
        }
      }
      __syncthreads();   // B1: ekv complete
      // MFMA2: wave quadrant (dh,eh), K = 128 tokens
#pragma unroll
      for (int k2 = 0; k2 < 4; k2++){
        bf16x8 af[2], bf2[2];
#pragma unroll
        for (int mi2 = 0; mi2 < 2; mi2++){
          int row = 32 * dh + 16 * mi2 + r15, g = k2 * 4 + q;
          af[mi2] = *(const bf16x8*)&sekv[row * 128 + ((g ^ (row & 15)) * 8)];
        }
#pragma unroll
        for (int ni2 = 0; ni2 < 2; ni2++){
          int row = 64 + 32 * eh + 16 * ni2 + r15, g = k2 * 4 + q;
          bf2[ni2] = *(const bf16x8*)&sekv[row * 128 + ((g ^ (row & 15)) * 8)];
        }
#pragma unroll
        for (int mi2 = 0; mi2 < 2; mi2++)
#pragma unroll
          for (int ni2 = 0; ni2 < 2; ni2++)
            acc2[hh][mi2][ni2] = __builtin_amdgcn_mfma_f32_16x16x32_bf16(
                af[mi2], bf2[ni2], acc2[hh][mi2][ni2], 0, 0, 0);
      }
      __syncthreads();   // B2: ekv consumed (next head / next sub may overwrite)
    }
  }
  // flush: deposit each head's 64x64 ctx partial into LDS, stream contiguously
  float* fbuf = (float*)sekv;
#pragma unroll
  for (int hh = 0; hh < 2; hh++){
    const int h = hp * 2 + hh;
#pragma unroll
    for (int mi2 = 0; mi2 < 2; mi2++)
#pragma unroll
      for (int ni2 = 0; ni2 < 2; ni2++)
#pragma unroll
        for (int r = 0; r < 4; r++){
          int d = 32 * dh + 16 * mi2 + 4 * q + r, e = 32 * eh + 16 * ni2 + r15;
          fbuf[d * 64 + e] = acc2[hh][mi2][ni2][r];
        }
    __syncthreads();
    float* dst = pctx + ((size_t)((b * 8 + h) * 32 + chunk)) * 4096 + tid * 16;
#pragma unroll
    for (int i = 0; i < 4; i++)
      *(float4*)(dst + 4 * i) = *(const float4*)(fbuf + tid * 16 + 4 * i);
    __syncthreads();
  }
  if (jq < 2 && r15 == 0){
#pragma unroll
    for (int hh = 0; hh < 2; hh++){
      const int h = hp * 2 + hh;
      float* rb = prs + ((size_t)((b * 8 + h) * 32 + chunk)) * 64;
#pragma unroll
      for (int mi = 0; mi < 2; mi++)
#pragma unroll
        for (int r = 0; r < 4; r++)
          rb[32 * jq + 16 * mi + 4 * q + r] = rs[hh][mi][r];
    }
  }
}

// ---------------------------------------------------------------------------
// ctxred: ctx[bh][4096] = sum_tt pctx[bh][tt][4096]; rowsum from prs
// ---------------------------------------------------------------------------
__global__ __launch_bounds__(256) void ctxred(const float* __restrict__ pctx,
    const float* __restrict__ prs, float* __restrict__ ctx,
    float* __restrict__ rowsum){
  const int bh = blockIdx.x, tid = threadIdx.x;
  const float* base = pctx + (size_t)bh * 32 * 4096 + tid * 16;
  float4 acc[4] = {};
  for (int t = 0; t < 32; t++){
#pragma unroll
    for (int i = 0; i < 4; i++){
      float4 v = *(const float4*)(base + (size_t)t * 4096 + 4 * i);
      acc[i].x += v.x; acc[i].y += v.y; acc[i].z += v.z; acc[i].w += v.w;
    }
  }
  float* cdst = ctx + (size_t)bh * 4096 + tid * 16;
#pragma unroll
  for (int i = 0; i < 4; i++) *(float4*)(cdst + 4 * i) = acc[i];
  if (tid < 64){
    const float* rb = prs + (size_t)bh * 32 * 64 + tid;
    float s = 0.f;
    for (int t = 0; t < 32; t++) s += rb[t * 64];
    rowsum[bh * 64 + tid] = s;
  }
}

// ---------------------------------------------------------------------------
// mker: M[c][d] = (1/rowsum[d]) * sum_e Wo[c][h*64+e] * ctx[b][h][d][e],
// output in MFMA A-fragment order (frag f = ((bh*2+wy)*4+mi)*2+ks).
// ---------------------------------------------------------------------------
__global__ __launch_bounds__(256) void mker(const float* __restrict__ ctx,
    const float* __restrict__ Wo, const float* __restrict__ rowsum,
    u16* __restrict__ mtf){
  __shared__ float ctxh[64][68];
  __shared__ float woht[64][132];
  const int tid = threadIdx.x;
  const int h = blockIdx.x, b = blockIdx.y;
  const int bh = b * 8 + h;
  const int e4 = tid & 15, r0 = tid >> 4;
#pragma unroll
  for (int p = 0; p < 4; p++){
    int d = r0 + p * 16;
    float4 v = *(const float4*)(ctx + ((size_t)bh * 64 + d) * 64 + 4 * e4);
    *(float4*)&ctxh[d][4 * e4] = v;
  }
#pragma unroll
  for (int p = 0; p < 8; p++){
    int c = r0 + p * 16;
    float4 v = *(const float4*)(Wo + (size_t)c * 512 + h * 64 + 4 * e4);
    woht[4 * e4 + 0][c] = v.x; woht[4 * e4 + 1][c] = v.y;
    woht[4 * e4 + 2][c] = v.z; woht[4 * e4 + 3][c] = v.w;
  }
  __syncthreads();
  const int cg = tid & 3, d = tid >> 2;
  const float inv = 1.f / rowsum[bh * 64 + d];
  float acc[32];
#pragma unroll
  for (int cc = 0; cc < 32; cc++) acc[cc] = 0.f;
  for (int e = 0; e < 64; e++){
    float cv = ctxh[d][e];
#pragma unroll
    for (int cc = 0; cc < 32; cc++) acc[cc] += cv * woht[e][cg + 4 * cc];
  }
  const int ks = d >> 5, lq = ((d >> 3) & 3) << 4, i = d & 7;
#pragma unroll
  for (int cc = 0; cc < 32; cc++){
    int c = cg + 4 * cc;
    int f = ((bh * 2 + (c >> 6)) * 4 + ((c >> 4) & 3)) * 2 + ks;
    mtf[(size_t)f * 512 + ((c & 15) | lq) * 8 + i] = f2bf(inv * acc[cc]);
  }
}

// ---------------------------------------------------------------------------
// qout R6: per-head colsum arrays (zeroed once) + double-buffered smP
// -> 2 barriers/head. Weights/M frags from global (register-resident).
// ---------------------------------------------------------------------------
__global__ __launch_bounds__(256, 2) void qout(const u16* __restrict__ xt,
    const u16* __restrict__ wqf, const float* __restrict__ bqs,
    const u16* __restrict__ mtf, const float* __restrict__ bo,
    float* __restrict__ out){
  __shared__ u16 smX[128 * 128];   // xs[t][k] swizzled, persistent
  __shared__ u16 smP[2][128 * 64]; // pT[t][d] swizzled, double-buffered
  __shared__ float cs[8][128];     // per-head colsum
  const int tid = threadIdx.x;
  const int tt = blockIdx.x;       // 128-token tiles
  const int b  = blockIdx.y;
  const int bh0 = b * 8;
  const int w = tid >> 6, l = tid & 63, r15 = l & 15, q = l >> 4;
  const int wy = w >> 1, wx = w & 1;
  const int t0 = tt * 128;

  { // stage xs[t][k] swizzled
    const u16* src = xt + (size_t)(b * N_ + t0) * 128;
    const int row = tid >> 1, gb = (tid & 1) * 8;
#pragma unroll
    for (int p = 0; p < 8; p++){
      int g = gb + p;
      *(uint4*)&smX[row * 128 + ((g ^ (row & 15)) * 8)] =
          *(const uint4*)&src[(size_t)row * 128 + g * 8];
    }
  }
  for (int i = tid; i < 1024; i += 256) ((float*)cs)[i] = 0.f;
  __syncthreads();

  f32x4 acc3[4][4] = {};
  for (int h = 0; h < 8; h++){
    u16* sp = smP[h & 1];
    bf16x8 wq[2][4];
    {
      const u16* base = wqf + (size_t)((h * 2 + wy) * 8) * 512 + l * 8;
#pragma unroll
      for (int mi = 0; mi < 2; mi++)
#pragma unroll
        for (int ks = 0; ks < 4; ks++)
          wq[mi][ks] = *(const bf16x8*)(base + (size_t)(mi * 4 + ks) * 512);
    }
    // MFMA1: D1[d 32 rows][t 64 cols], K=128
    f32x4 acc1[2][4] = {};
#pragma unroll
    for (int ks = 0; ks < 4; ks++){
      bf16x8 bfr[4];
#pragma unroll
      for (int ni = 0; ni < 4; ni++){
        int row = 64 * wx + 16 * ni + r15, g = ks * 4 + q;
        bfr[ni] = *(const bf16x8*)&smX[row * 128 + ((g ^ (row & 15)) * 8)];
      }
#pragma unroll
      for (int mi = 0; mi < 2; mi++)
#pragma unroll
        for (int ni = 0; ni < 4; ni++)
          acc1[mi][ni] = __builtin_amdgcn_mfma_f32_16x16x32_bf16(
              wq[mi][ks], bfr[ni], acc1[mi][ni], 0, 0, 0);
    }
    float ev[2][4][4];
#pragma unroll
    for (int mi = 0; mi < 2; mi++)
#pragma unroll
      for (int r = 0; r < 4; r++){
        int d = 32 * wy + 16 * mi + 4 * q + r;
        float bias = bqs[h * 64 + d];
#pragma unroll
        for (int ni = 0; ni < 4; ni++)
          ev[mi][ni][r] = __expf(acc1[mi][ni][r] + bias);
      }
#pragma unroll
    for (int ni = 0; ni < 4; ni++){
      float s = 0.f;
#pragma unroll
      for (int mi = 0; mi < 2; mi++)
#pragma unroll
        for (int r = 0; r < 4; r++) s += ev[mi][ni][r];
      s += __shfl_xor(s, 16); s += __shfl_xor(s, 32);
      if (q == 0) atomicAdd(&cs[h][64 * wx + 16 * ni + r15], s);
    }
    __syncthreads();   // B1: colsum complete
    bf16x8 maf[4][2];
    {
      const u16* base = mtf + (size_t)(((bh0 + h) * 2 + wy) * 8) * 512 + l * 8;
#pragma unroll
      for (int mi = 0; mi < 4; mi++)
#pragma unroll
        for (int ks = 0; ks < 2; ks++)
          maf[mi][ks] = *(const bf16x8*)(base + (size_t)(mi * 2 + ks) * 512);
    }
#pragma unroll
    for (int ni = 0; ni < 4; ni++){
      int t = 64 * wx + 16 * ni + r15;
      float ci = 1.f / cs[h][t];
#pragma unroll
      for (int mi = 0; mi < 2; mi++)
#pragma unroll
        for (int r = 0; r < 4; r++){
          int d = 32 * wy + 16 * mi + 4 * q + r;
          sp[t * 64 + (((d >> 3) ^ (t & 7)) * 8) + (d & 7)] = f2bf(ev[mi][ni][r] * ci);
        }
    }
    __syncthreads();   // B2: smP[h&1] ready
    // MFMA2: out tile 64c x 64t, K=64
#pragma unroll
    for (int ks = 0; ks < 2; ks++){
      bf16x8 bfr[4];
#pragma unroll
      for (int ni = 0; ni < 4; ni++){
        int t = 64 * wx + 16 * ni + r15;
        bfr[ni] = *(const bf16x8*)&sp[t * 64 + (((4 * ks + q) ^ (t & 7)) * 8)];
      }
#pragma unroll
      for (int mi = 0; mi < 4; mi++)
#pragma unroll
        for (int ni = 0; ni < 4; ni++)
          acc3[mi][ni] = __builtin_amdgcn_mfma_f32_16x16x32_bf16(
              maf[mi][ks], bfr[ni], acc3[mi][ni], 0, 0, 0);
    }
    // no 3rd barrier: double-buffered smP — writes of head h+2 are fenced by B2(h+1)
  }
#pragma unroll
  for (int mi = 0; mi < 4; mi++)
#pragma unroll
    for (int r = 0; r < 4; r++){
      int c = 64 * wy + 16 * mi + 4 * q + r;
      float bb = bo[c];
#pragma unroll
      for (int ni = 0; ni < 4; ni++){
        int t = 64 * wx + 16 * ni + r15;
        out[(size_t)(b * 128 + c) * N_ + t0 + t] = acc3[mi][ni][r] + bb;
      }
    }
}

// ---------------------------------------------------------------------------
extern "C" void kernel_launch(void* const* d_in, const int* in_sizes, int n_in,
                              void* d_out, int out_size, void* d_ws, size_t ws_size,
                              hipStream_t stream){
  const float* x  = (const float*)d_in[0];
  const float* Wq = (const float*)d_in[1];
  const float* bq = (const float*)d_in[2];
  const float* Wk = (const float*)d_in[3];
  const float* bk = (const float*)d_in[4];
  const float* Wv = (const float*)d_in[5];
  const float* bv = (const float*)d_in[6];
  const float* Wo = (const float*)d_in[7];
  const float* bo = (const float*)d_in[8];
  float* out = (float*)d_out;

  char* ws = (char*)d_ws;
  u16*   xt     = (u16*)ws;                         // 16 MiB
  u16*   wkvf   = (u16*)(ws + 16777216);            // 256 KiB
  u16*   wqf    = (u16*)(ws + 17039360);            // 128 KiB
  u16*   mtf    = (u16*)(ws + 17170432);            // 512 KiB
  float* bkv    = (float*)(ws + 17694720);          // 4 KiB
  float* bqs    = (float*)(ws + 17698816);          // 2 KiB
  float* rowsum = (float*)(ws + 17700864);          // 8 KiB
  float* ctx    = (float*)(ws + 17709056);          // 512 KiB
  float* pctx   = (float*)(ws + 18233344);          // 16 MiB
  float* prs    = (float*)(ws + 35010560);          // 512 KiB

  prep <<<96, 256, 0, stream>>>(Wq, bq, Wk, bk, Wv, bv, wkvf, wqf, bkv, bqs);
  convx<<<dim3(256, 4), 256, 0, stream>>>(x, xt);
  kvctx<<<dim3(32, 4, 4), 256, 0, stream>>>(xt, wkvf, bkv, pctx, prs);
  ctxred<<<32, 256, 0, stream>>>(pctx, prs, ctx, rowsum);
  mker <<<dim3(8, 4), 256, 0, stream>>>(ctx, Wo, rowsum, mtf);
  qout <<<dim3(128, 4), 256, 0, stream>>>(xt, wqf, bqs, mtf, bo, out);
}

// Round 7
// 237.851 us; speedup vs baseline: 3.1790x; 1.0389x over previous
//
#include <hip/hip_runtime.h>

typedef unsigned short u16;
typedef __bf16 bf16x8 __attribute__((ext_vector_type(8)));
typedef float f32x4 __attribute__((ext_vector_type(4)));

#define N_ 16384
#define SCALE 0.35355339059327379f   // 64^-0.25

__device__ __forceinline__ u16 f2bf(float f){
  union { float f; unsigned int i; } v; v.f = f;
  unsigned int b = v.i;
  return (u16)((b + 0x7FFFu + ((b >> 16) & 1u)) >> 16);
}
__device__ __forceinline__ unsigned int pack2bf(float a, float b){
  return ((unsigned int)f2bf(b) << 16) | (unsigned int)f2bf(a);
}

// ---------------------------------------------------------------------------
// prep (unchanged layouts): A/B-frag order for 16x16x32:
// lane = (row&15) | (((k>>3)&3)<<4), elem = k&7, k = ks*32 + (lane>>4)*8 + elem
// wkvf: f = (h*8 + jt)*4 + ks, row j = 16*jt + (l&15) of [SCALE*Wk_h; Wv_h]
// wqf:  f = (h*4 + dt)*4 + ks, row d = 16*dt + (l&15) of SCALE*Wq_h
// ---------------------------------------------------------------------------
__global__ __launch_bounds__(256) void prep(const float* __restrict__ Wq,
    const float* __restrict__ bq, const float* __restrict__ Wk,
    const float* __restrict__ bk, const float* __restrict__ Wv,
    const float* __restrict__ bv, u16* __restrict__ wkvf, u16* __restrict__ wqf,
    float* __restrict__ bkv, float* __restrict__ bqs){
  const int T = blockIdx.x * 256 + threadIdx.x;   // 0..24575
  if (T < 1024){
    int jj = T & 127, h = T >> 7;
    bkv[T] = (jj < 64) ? SCALE * bk[h * 64 + jj] : bv[h * 64 + jj - 64];
  } else if (T < 1536){
    bqs[T - 1024] = SCALE * bq[T - 1024];
  }
  const float* src; float sc; u16* dst;
  if (T < 16384){
    int l = T & 63, f = T >> 6;
    int ks = f & 3, jt = (f >> 2) & 7, h = f >> 5;
    int jj = 16 * jt + (l & 15);
    int k0 = ks * 32 + (l >> 4) * 8;
    if (jj < 64){ src = Wk + (size_t)(h * 64 + jj) * 128 + k0; sc = SCALE; }
    else        { src = Wv + (size_t)(h * 64 + jj - 64) * 128 + k0; sc = 1.f; }
    dst = wkvf + (size_t)f * 512 + l * 8;
  } else {
    int T2 = T - 16384;
    int l = T2 & 63, f = T2 >> 6;
    int ks = f & 3, dt = (f >> 2) & 3, h = f >> 4;
    int d = 16 * dt + (l & 15);
    int k0 = ks * 32 + (l >> 4) * 8;
    src = Wq + (size_t)(h * 64 + d) * 128 + k0; sc = SCALE;
    dst = wqf + (size_t)f * 512 + l * 8;
  }
  float4 a = *(const float4*)src, c = *(const float4*)(src + 4);
  ushort4 o0, o1;
  o0.x = f2bf(sc * a.x); o0.y = f2bf(sc * a.y); o0.z = f2bf(sc * a.z); o0.w = f2bf(sc * a.w);
  o1.x = f2bf(sc * c.x); o1.y = f2bf(sc * c.y); o1.z = f2bf(sc * c.z); o1.w = f2bf(sc * c.w);
  *(ushort4*)dst = o0; *(ushort4*)(dst + 4) = o1;
}

// ---------------------------------------------------------------------------
// convx: x[b][128 k][N] fp32 -> xt[b][N t][128 k] bf16
// ---------------------------------------------------------------------------
__global__ __launch_bounds__(256) void convx(const float* __restrict__ x,
                                             u16* __restrict__ xt){
  __shared__ u16 lt[64][136];
  const int tid = threadIdx.x;
  const int t0 = blockIdx.x * 64;
  const int b  = blockIdx.y;
  {
    const int t4 = tid & 15, kr = tid >> 4;
#pragma unroll
    for (int p = 0; p < 8; p++){
      int k = kr + p * 16;
      float4 v = *(const float4*)(x + (size_t)(b * 128 + k) * N_ + t0 + 4 * t4);
      lt[4 * t4 + 0][k] = f2bf(v.x);
      lt[4 * t4 + 1][k] = f2bf(v.y);
      lt[4 * t4 + 2][k] = f2bf(v.z);
      lt[4 * t4 + 3][k] = f2bf(v.w);
    }
  }
  __syncthreads();
  {
    const int t = tid >> 2, kq = tid & 3;
#pragma unroll
    for (int p = 0; p < 4; p++)
      *(uint4*)(xt + (size_t)(b * N_ + t0 + t) * 128 + kq * 32 + p * 8) =
          *(const uint4*)&lt[t][kq * 32 + p * 8];
  }
}

// ---------------------------------------------------------------------------
// kvctx R7: swapped MFMA1 (D[t][j] = x·W^T) -> b64 epilogue writes; weights in
// regs (1:4 read:MFMA); MFMA2 per-wave 32-token K-slices (regs across subs).
// Waves: (th = t-half for MFMA1, jh = j-half). 3 barriers/sub, 56 LDS inst/wave/sub.
// sekv b64 swizzle: 8B granule g ^ (2*(row&15)) — even mask keeps b128 halves ordered.
// ---------------------------------------------------------------------------
__global__ __launch_bounds__(256, 2) void kvctx(const u16* __restrict__ xt,
    const u16* __restrict__ wkvf, const float* __restrict__ bkv,
    float* __restrict__ pctx, float* __restrict__ prs){
  __shared__ u16 smem[32768];   // [0,16384): sx[128t][128k] ; [16384,32768): sekv[128j][128t]
  const int tid = threadIdx.x;
  const int chunk = blockIdx.x, h = blockIdx.y, b = blockIdx.z;
  const int w = tid >> 6, l = tid & 63, r15 = l & 15, q = l >> 4;
  const int th = w & 1, jh = w >> 1;
  const int srow = tid >> 1, sg = (tid & 1) * 8;

  bf16x8 wf[4][4];   // B-frags: rows j = jh*64+16ni+r15
#pragma unroll
  for (int ni = 0; ni < 4; ni++)
#pragma unroll
    for (int ks = 0; ks < 4; ks++)
      wf[ni][ks] = *(const bf16x8*)(wkvf +
          (size_t)((h * 8 + 4 * jh + ni) * 4 + ks) * 512 + l * 8);
  float barr[4];
#pragma unroll
  for (int ni = 0; ni < 4; ni++)
    barr[ni] = bkv[h * 128 + jh * 64 + 16 * ni + r15];

  const size_t tok0 = (size_t)b * N_ + chunk * 512;
  f32x4 acc2[4][4] = {};
  float rs[4] = {0.f, 0.f, 0.f, 0.f};
  u16* sekv = smem + 16384;

  for (int sub = 0; sub < 4; sub++){
    { // stage sx
      const u16* src = xt + (tok0 + sub * 128 + srow) * 128;
      uint4 v[8];
#pragma unroll
      for (int p = 0; p < 8; p++) v[p] = *(const uint4*)(src + (sg + p) * 8);
#pragma unroll
      for (int p = 0; p < 8; p++){
        int g = sg + p;
        *(uint4*)&smem[srow * 128 + ((g ^ (srow & 15)) * 8)] = v[p];
      }
    }
    __syncthreads();   // B0: sx ready
    // MFMA1: wave tile 64t(mi) x 64j(ni), K=128; A = x, B = weights
    f32x4 acc1[4][4] = {};
#pragma unroll
    for (int ks = 0; ks < 4; ks++){
      bf16x8 xa[4];
#pragma unroll
      for (int mi = 0; mi < 4; mi++){
        int t = th * 64 + 16 * mi + r15, g = ks * 4 + q;
        xa[mi] = *(const bf16x8*)&smem[t * 128 + ((g ^ (t & 15)) * 8)];
      }
#pragma unroll
      for (int mi = 0; mi < 4; mi++)
#pragma unroll
        for (int ni = 0; ni < 4; ni++)
          acc1[mi][ni] = __builtin_amdgcn_mfma_f32_16x16x32_bf16(
              xa[mi], wf[ni][ks], acc1[mi][ni], 0, 0, 0);
    }
    // epilogue: lane holds 4 consecutive t at fixed j -> one b64 per (mi,ni)
#pragma unroll
    for (int ni = 0; ni < 4; ni++){
      const float bb = barr[ni];
      const int j = jh * 64 + 16 * ni + r15;
      float ps = 0.f;
#pragma unroll
      for (int mi = 0; mi < 4; mi++){
        float vals[4];
#pragma unroll
        for (int r = 0; r < 4; r++) vals[r] = acc1[mi][ni][r] + bb;
        if (jh == 0){
#pragma unroll
          for (int r = 0; r < 4; r++){ vals[r] = __expf(vals[r]); ps += vals[r]; }
        }
        uint2 pk;
        pk.x = pack2bf(vals[0], vals[1]);
        pk.y = pack2bf(vals[2], vals[3]);
        int g8 = 16 * th + 4 * mi + q;          // t-granule (8B = 4 t)
        int g8s = g8 ^ (2 * r15);
        *(uint2*)&sekv[j * 128 + g8s * 4] = pk;
      }
      if (jh == 0){
        ps += __shfl_xor(ps, 16); ps += __shfl_xor(ps, 32);
        rs[ni] += ps;
      }
    }
    __syncthreads();   // B1: ekv ready
    // MFMA2: wave K-slice t = w*32..w*32+31; ctx 64d x 64e
    {
      bf16x8 ka[4], va[4];
      const int g8s = (8 * w + 2 * q) ^ (2 * r15);
#pragma unroll
      for (int mi2 = 0; mi2 < 4; mi2++){
        int d = 16 * mi2 + r15;
        ka[mi2] = *(const bf16x8*)&sekv[d * 128 + g8s * 4];
      }
#pragma unroll
      for (int ni2 = 0; ni2 < 4; ni2++){
        int e = 16 * ni2 + r15;
        va[ni2] = *(const bf16x8*)&sekv[(64 + e) * 128 + g8s * 4];
      }
#pragma unroll
      for (int mi2 = 0; mi2 < 4; mi2++)
#pragma unroll
        for (int ni2 = 0; ni2 < 4; ni2++)
          acc2[mi2][ni2] = __builtin_amdgcn_mfma_f32_16x16x32_bf16(
              ka[mi2], va[ni2], acc2[mi2][ni2], 0, 0, 0);
    }
    __syncthreads();   // B2: ekv consumed
  }
  // cross-wave ctx reduce through LDS (smem dead), contiguous 16 KiB stream out
  float* fb = (float*)smem;   // 16384 floats = 4 regions of 4096
#pragma unroll
  for (int mi2 = 0; mi2 < 4; mi2++)
#pragma unroll
    for (int ni2 = 0; ni2 < 4; ni2++)
#pragma unroll
      for (int r = 0; r < 4; r++){
        int d = 16 * mi2 + 4 * q + r, e = 16 * ni2 + r15;
        fb[w * 4096 + d * 64 + e] = acc2[mi2][ni2][r];
      }
  __syncthreads();
  {
    float* dst = pctx + ((size_t)((b * 8 + h) * 32 + chunk)) * 4096 + tid * 16;
#pragma unroll
    for (int i = 0; i < 4; i++){
      int o = tid * 16 + 4 * i;
      float4 a = *(const float4*)(fb + o);
      float4 c = *(const float4*)(fb + 4096 + o);
      float4 d = *(const float4*)(fb + 8192 + o);
      float4 e = *(const float4*)(fb + 12288 + o);
      float4 s;
      s.x = a.x + c.x + d.x + e.x; s.y = a.y + c.y + d.y + e.y;
      s.z = a.z + c.z + d.z + e.z; s.w = a.w + c.w + d.w + e.w;
      *(float4*)(dst + 4 * i) = s;
    }
  }
  if (jh == 0 && q == 0){
    float* rb = prs + ((size_t)((b * 8 + h) * 32 + chunk)) * 128 + th * 64;
#pragma unroll
    for (int ni = 0; ni < 4; ni++) rb[16 * ni + r15] = rs[ni];
  }
}

// ---------------------------------------------------------------------------
// ctxred: ctx[bh][4096] = sum_tt pctx; rowsum[bh][64] from prs (two th-halves)
// ---------------------------------------------------------------------------
__global__ __launch_bounds__(256) void ctxred(const float* __restrict__ pctx,
    const float* __restrict__ prs, float* __restrict__ ctx,
    float* __restrict__ rowsum){
  const int bh = blockIdx.x, tid = threadIdx.x;
  const float* base = pctx + (size_t)bh * 32 * 4096 + tid * 16;
  float4 acc[4] = {};
  for (int t = 0; t < 32; t++){
#pragma unroll
    for (int i = 0; i < 4; i++){
      float4 v = *(const float4*)(base + (size_t)t * 4096 + 4 * i);
      acc[i].x += v.x; acc[i].y += v.y; acc[i].z += v.z; acc[i].w += v.w;
    }
  }
  float* cdst = ctx + (size_t)bh * 4096 + tid * 16;
#pragma unroll
  for (int i = 0; i < 4; i++) *(float4*)(cdst + 4 * i) = acc[i];
  if (tid < 64){
    const float* rb = prs + (size_t)bh * 32 * 128 + tid;
    float s = 0.f;
    for (int t = 0; t < 32; t++) s += rb[t * 128] + rb[t * 128 + 64];
    rowsum[bh * 64 + tid] = s;
  }
}

// ---------------------------------------------------------------------------
// mker: M[c][d] = (1/rowsum[d]) * sum_e Wo[c][h*64+e] * ctx[b][h][d][e]
// stored as A-frags for qout MFMA2: f = (bh*8 + mi)*2 + ks,
// lane = (c&15)|(((d>>3)&3)<<4), elem = d&7, mi = c>>4, ks = d>>5.
// ---------------------------------------------------------------------------
__global__ __launch_bounds__(256) void mker(const float* __restrict__ ctx,
    const float* __restrict__ Wo, const float* __restrict__ rowsum,
    u16* __restrict__ mtf){
  __shared__ float ctxh[64][68];
  __shared__ float woht[64][132];
  const int tid = threadIdx.x;
  const int h = blockIdx.x, b = blockIdx.y;
  const int bh = b * 8 + h;
  const int e4 = tid & 15, r0 = tid >> 4;
#pragma unroll
  for (int p = 0; p < 4; p++){
    int d = r0 + p * 16;
    float4 v = *(const float4*)(ctx + ((size_t)bh * 64 + d) * 64 + 4 * e4);
    *(float4*)&ctxh[d][4 * e4] = v;
  }
#pragma unroll
  for (int p = 0; p < 8; p++){
    int c = r0 + p * 16;
    float4 v = *(const float4*)(Wo + (size_t)c * 512 + h * 64 + 4 * e4);
    woht[4 * e4 + 0][c] = v.x; woht[4 * e4 + 1][c] = v.y;
    woht[4 * e4 + 2][c] = v.z; woht[4 * e4 + 3][c] = v.w;
  }
  __syncthreads();
  const int cg = tid & 3, d = tid >> 2;
  const float inv = 1.f / rowsum[bh * 64 + d];
  float acc[32];
#pragma unroll
  for (int cc = 0; cc < 32; cc++) acc[cc] = 0.f;
  for (int e = 0; e < 64; e++){
    float cv = ctxh[d][e];
#pragma unroll
    for (int cc = 0; cc < 32; cc++) acc[cc] += cv * woht[e][cg + 4 * cc];
  }
  const int ks = d >> 5, lq = ((d >> 3) & 3) << 4, el = d & 7;
#pragma unroll
  for (int cc = 0; cc < 32; cc++){
    int c = cg + 4 * cc;
    mtf[((size_t)(bh * 8 + (c >> 4)) * 2 + ks) * 512 + ((c & 15) | lq) * 8 + el]
        = f2bf(inv * acc[cc]);
  }
}

// ---------------------------------------------------------------------------
// qout R7: barrier-free head loop. Wave owns 32 tokens. MFMA1 D[d][t] with
// wq A-frags from global; colsum fully in-register (shfl over q); normalized
// p -> wave-private LDS [32t][64d] (b64 writes, even-mask swizzle);
// MFMA2: out[c][t] += M·p with M A-frags from global. One barrier total.
// ---------------------------------------------------------------------------
__global__ __launch_bounds__(256, 2) void qout(const u16* __restrict__ xt,
    const u16* __restrict__ wqf, const float* __restrict__ bqs,
    const u16* __restrict__ mtf, const float* __restrict__ bo,
    float* __restrict__ out){
  __shared__ u16 smX[16384];     // [128t][128k] swizzled, persistent
  __shared__ u16 smP[4][2048];   // per-wave p[32t][64d]
  const int tid = threadIdx.x;
  const int tt = blockIdx.x, b = blockIdx.y;
  const int w = tid >> 6, l = tid & 63, r15 = l & 15, q = l >> 4;
  const int t0 = tt * 128;
  const int m7 = 2 * (r15 & 7);   // even swizzle mask for smP

  { // stage smX
    const u16* src = xt + (size_t)(b * N_ + t0) * 128;
    const int row = tid >> 1, gb = (tid & 1) * 8;
#pragma unroll
    for (int p = 0; p < 8; p++){
      int g = gb + p;
      *(uint4*)&smX[row * 128 + ((g ^ (row & 15)) * 8)] =
          *(const uint4*)&src[(size_t)row * 128 + g * 8];
    }
  }
  __syncthreads();   // the only barrier

  u16* sp = smP[w];
  f32x4 acc3[8][2] = {};
  for (int h = 0; h < 8; h++){
    float bq_[4][4];
#pragma unroll
    for (int mi = 0; mi < 4; mi++)
#pragma unroll
      for (int r = 0; r < 4; r++)
        bq_[mi][r] = bqs[h * 64 + 16 * mi + 4 * q + r];
    // MFMA1: D[d 64][t 32], K=128; A = wq, B = x
    f32x4 acc1[4][2] = {};
#pragma unroll
    for (int ks = 0; ks < 4; ks++){
      bf16x8 wqv[4];
#pragma unroll
      for (int mi = 0; mi < 4; mi++)
        wqv[mi] = *(const bf16x8*)(wqf +
            (size_t)((h * 4 + mi) * 4 + ks) * 512 + l * 8);
      bf16x8 xb[2];
#pragma unroll
      for (int ni = 0; ni < 2; ni++){
        int tl = w * 32 + 16 * ni + r15, g = ks * 4 + q;
        xb[ni] = *(const bf16x8*)&smX[tl * 128 + ((g ^ (tl & 15)) * 8)];
      }
#pragma unroll
      for (int mi = 0; mi < 4; mi++)
#pragma unroll
        for (int ni = 0; ni < 2; ni++)
          acc1[mi][ni] = __builtin_amdgcn_mfma_f32_16x16x32_bf16(
              wqv[mi], xb[ni], acc1[mi][ni], 0, 0, 0);
    }
    // exp + in-wave colsum + normalized p store (wave-private)
#pragma unroll
    for (int ni = 0; ni < 2; ni++){
      float ps = 0.f;
#pragma unroll
      for (int mi = 0; mi < 4; mi++)
#pragma unroll
        for (int r = 0; r < 4; r++){
          float e = __expf(acc1[mi][ni][r] + bq_[mi][r]);
          acc1[mi][ni][r] = e; ps += e;
        }
      ps += __shfl_xor(ps, 16); ps += __shfl_xor(ps, 32);
      const float ci = 1.f / ps;
      const int tl = 16 * ni + r15;
#pragma unroll
      for (int mi = 0; mi < 4; mi++){
        uint2 pk;
        pk.x = pack2bf(acc1[mi][ni][0] * ci, acc1[mi][ni][1] * ci);
        pk.y = pack2bf(acc1[mi][ni][2] * ci, acc1[mi][ni][3] * ci);
        int g8s = (4 * mi + q) ^ m7;     // d-granule (8B = 4 d)
        *(uint2*)&sp[tl * 64 + g8s * 4] = pk;
      }
    }
    // MFMA2: out[c 128][t 32] += M_h · p, K=64
#pragma unroll
    for (int ks2 = 0; ks2 < 2; ks2++){
      bf16x8 pb[2];
      const int g8s = (8 * ks2 + 2 * q) ^ m7;
#pragma unroll
      for (int ni = 0; ni < 2; ni++){
        int tl = 16 * ni + r15;
        pb[ni] = *(const bf16x8*)&sp[tl * 64 + g8s * 4];
      }
#pragma unroll
      for (int half = 0; half < 2; half++){
        bf16x8 mf[4];
#pragma unroll
        for (int mm = 0; mm < 4; mm++)
          mf[mm] = *(const bf16x8*)(mtf +
              ((size_t)((b * 8 + h) * 8 + half * 4 + mm) * 2 + ks2) * 512 + l * 8);
#pragma unroll
        for (int mm = 0; mm < 4; mm++)
#pragma unroll
          for (int ni = 0; ni < 2; ni++)
            acc3[half * 4 + mm][ni] = __builtin_amdgcn_mfma_f32_16x16x32_bf16(
                mf[mm], pb[ni], acc3[half * 4 + mm][ni], 0, 0, 0);
      }
    }
  }
#pragma unroll
  for (int mi = 0; mi < 8; mi++)
#pragma unroll
    for (int r = 0; r < 4; r++){
      int c = 16 * mi + 4 * q + r;
      float bb = bo[c];
#pragma unroll
      for (int ni = 0; ni < 2; ni++){
        int t = t0 + w * 32 + 16 * ni + r15;
        out[(size_t)(b * 128 + c) * N_ + t] = acc3[mi][ni][r] + bb;
      }
    }
}

// ---------------------------------------------------------------------------
extern "C" void kernel_launch(void* const* d_in, const int* in_sizes, int n_in,
                              void* d_out, int out_size, void* d_ws, size_t ws_size,
                              hipStream_t stream){
  const float* x  = (const float*)d_in[0];
  const float* Wq = (const float*)d_in[1];
  const float* bq = (const float*)d_in[2];
  const float* Wk = (const float*)d_in[3];
  const float* bk = (const float*)d_in[4];
  const float* Wv = (const float*)d_in[5];
  const float* bv = (const float*)d_in[6];
  const float* Wo = (const float*)d_in[7];
  const float* bo = (const float*)d_in[8];
  float* out = (float*)d_out;

  char* ws = (char*)d_ws;
  u16*   xt     = (u16*)ws;                         // 16 MiB
  u16*   wkvf   = (u16*)(ws + 16777216);            // 256 KiB
  u16*   wqf    = (u16*)(ws + 17039360);            // 128 KiB
  u16*   mtf    = (u16*)(ws + 17170432);            // 512 KiB
  float* bkv    = (float*)(ws + 17694720);          // 4 KiB
  float* bqs    = (float*)(ws + 17698816);          // 2 KiB
  float* rowsum = (float*)(ws + 17700864);          // 8 KiB
  float* ctx    = (float*)(ws + 17709056);          // 512 KiB
  float* pctx   = (float*)(ws + 18233344);          // 16 MiB
  float* prs    = (float*)(ws + 35010560);          // 512 KiB

  prep <<<96, 256, 0, stream>>>(Wq, bq, Wk, bk, Wv, bv, wkvf, wqf, bkv, bqs);
  convx<<<dim3(256, 4), 256, 0, stream>>>(x, xt);
  kvctx<<<dim3(32, 8, 4), 256, 0, stream>>>(xt, wkvf, bkv, pctx, prs);
  ctxred<<<32, 256, 0, stream>>>(pctx, prs, ctx, rowsum);
  mker <<<dim3(8, 4), 256, 0, stream>>>(ctx, Wo, rowsum, mtf);
  qout <<<dim3(128, 4), 256, 0, stream>>>(xt, wqf, bqs, mtf, bo, out);
}

// Round 8
// 206.190 us; speedup vs baseline: 3.6671x; 1.1536x over previous
//
#include <hip/hip_runtime.h>

typedef unsigned short u16;
typedef __bf16 bf16x8 __attribute__((ext_vector_type(8)));
typedef float f32x4 __attribute__((ext_vector_type(4)));

#define N_ 16384
#define SCALE 0.35355339059327379f   // 64^-0.25

__device__ __forceinline__ u16 f2bf(float f){
  union { float f; unsigned int i; } v; v.f = f;
  unsigned int b = v.i;
  return (u16)((b + 0x7FFFu + ((b >> 16) & 1u)) >> 16);
}
__device__ __forceinline__ unsigned int pack2bf(float a, float b){
  return ((unsigned int)f2bf(b) << 16) | (unsigned int)f2bf(a);
}

// ---------------------------------------------------------------------------
// prep: A/B-frag order for 16x16x32: lane = (row&15)|(((k>>3)&3)<<4), elem=k&7.
// wkvf: f = (h*8 + jt)*4 + ks, row j = 16*jt + (l&15) of [SCALE*Wk_h; Wv_h]
// wqf:  f = (h*4 + dt)*4 + ks, row d = 16*dt + (l&15) of SCALE*Wq_h
// ---------------------------------------------------------------------------
__global__ __launch_bounds__(256) void prep(const float* __restrict__ Wq,
    const float* __restrict__ bq, const float* __restrict__ Wk,
    const float* __restrict__ bk, const float* __restrict__ Wv,
    const float* __restrict__ bv, u16* __restrict__ wkvf, u16* __restrict__ wqf,
    float* __restrict__ bkv, float* __restrict__ bqs){
  const int T = blockIdx.x * 256 + threadIdx.x;   // 0..24575
  if (T < 1024){
    int jj = T & 127, h = T >> 7;
    bkv[T] = (jj < 64) ? SCALE * bk[h * 64 + jj] : bv[h * 64 + jj - 64];
  } else if (T < 1536){
    bqs[T - 1024] = SCALE * bq[T - 1024];
  }
  const float* src; float sc; u16* dst;
  if (T < 16384){
    int l = T & 63, f = T >> 6;
    int ks = f & 3, jt = (f >> 2) & 7, h = f >> 5;
    int jj = 16 * jt + (l & 15);
    int k0 = ks * 32 + (l >> 4) * 8;
    if (jj < 64){ src = Wk + (size_t)(h * 64 + jj) * 128 + k0; sc = SCALE; }
    else        { src = Wv + (size_t)(h * 64 + jj - 64) * 128 + k0; sc = 1.f; }
    dst = wkvf + (size_t)f * 512 + l * 8;
  } else {
    int T2 = T - 16384;
    int l = T2 & 63, f = T2 >> 6;
    int ks = f & 3, dt = (f >> 2) & 3, h = f >> 4;
    int d = 16 * dt + (l & 15);
    int k0 = ks * 32 + (l >> 4) * 8;
    src = Wq + (size_t)(h * 64 + d) * 128 + k0; sc = SCALE;
    dst = wqf + (size_t)f * 512 + l * 8;
  }
  float4 a = *(const float4*)src, c = *(const float4*)(src + 4);
  ushort4 o0, o1;
  o0.x = f2bf(sc * a.x); o0.y = f2bf(sc * a.y); o0.z = f2bf(sc * a.z); o0.w = f2bf(sc * a.w);
  o1.x = f2bf(sc * c.x); o1.y = f2bf(sc * c.y); o1.z = f2bf(sc * c.z); o1.w = f2bf(sc * c.w);
  *(ushort4*)dst = o0; *(ushort4*)(dst + 4) = o1;
}

// ---------------------------------------------------------------------------
// convx: x[b][128 k][N] fp32 -> xt[b][N t][128 k] bf16
// ---------------------------------------------------------------------------
__global__ __launch_bounds__(256) void convx(const float* __restrict__ x,
                                             u16* __restrict__ xt){
  __shared__ u16 lt[64][136];
  const int tid = threadIdx.x;
  const int t0 = blockIdx.x * 64;
  const int b  = blockIdx.y;
  {
    const int t4 = tid & 15, kr = tid >> 4;
#pragma unroll
    for (int p = 0; p < 8; p++){
      int k = kr + p * 16;
      float4 v = *(const float4*)(x + (size_t)(b * 128 + k) * N_ + t0 + 4 * t4);
      lt[4 * t4 + 0][k] = f2bf(v.x);
      lt[4 * t4 + 1][k] = f2bf(v.y);
      lt[4 * t4 + 2][k] = f2bf(v.z);
      lt[4 * t4 + 3][k] = f2bf(v.w);
    }
  }
  __syncthreads();
  {
    const int t = tid >> 2, kq = tid & 3;
#pragma unroll
    for (int p = 0; p < 4; p++)
      *(uint4*)(xt + (size_t)(b * N_ + t0 + t) * 128 + kq * 32 + p * 8) =
          *(const uint4*)&lt[t][kq * 32 + p * 8];
  }
}

// ---------------------------------------------------------------------------
// kvctx (R7 verbatim): swapped MFMA1 (D[t][j] = x·W^T), b64 epilogue writes,
// weights in regs, MFMA2 per-wave 32-token K-slices accumulated in regs.
// ---------------------------------------------------------------------------
__global__ __launch_bounds__(256, 2) void kvctx(const u16* __restrict__ xt,
    const u16* __restrict__ wkvf, const float* __restrict__ bkv,
    float* __restrict__ pctx, float* __restrict__ prs){
  __shared__ u16 smem[32768];   // [0,16384): sx[128t][128k] ; [16384,32768): sekv[128j][128t]
  const int tid = threadIdx.x;
  const int chunk = blockIdx.x, h = blockIdx.y, b = blockIdx.z;
  const int w = tid >> 6, l = tid & 63, r15 = l & 15, q = l >> 4;
  const int th = w & 1, jh = w >> 1;
  const int srow = tid >> 1, sg = (tid & 1) * 8;

  bf16x8 wf[4][4];
#pragma unroll
  for (int ni = 0; ni < 4; ni++)
#pragma unroll
    for (int ks = 0; ks < 4; ks++)
      wf[ni][ks] = *(const bf16x8*)(wkvf +
          (size_t)((h * 8 + 4 * jh + ni) * 4 + ks) * 512 + l * 8);
  float barr[4];
#pragma unroll
  for (int ni = 0; ni < 4; ni++)
    barr[ni] = bkv[h * 128 + jh * 64 + 16 * ni + r15];

  const size_t tok0 = (size_t)b * N_ + chunk * 512;
  f32x4 acc2[4][4] = {};
  float rs[4] = {0.f, 0.f, 0.f, 0.f};
  u16* sekv = smem + 16384;

  for (int sub = 0; sub < 4; sub++){
    {
      const u16* src = xt + (tok0 + sub * 128 + srow) * 128;
      uint4 v[8];
#pragma unroll
      for (int p = 0; p < 8; p++) v[p] = *(const uint4*)(src + (sg + p) * 8);
#pragma unroll
      for (int p = 0; p < 8; p++){
        int g = sg + p;
        *(uint4*)&smem[srow * 128 + ((g ^ (srow & 15)) * 8)] = v[p];
      }
    }
    __syncthreads();
    f32x4 acc1[4][4] = {};
#pragma unroll
    for (int ks = 0; ks < 4; ks++){
      bf16x8 xa[4];
#pragma unroll
      for (int mi = 0; mi < 4; mi++){
        int t = th * 64 + 16 * mi + r15, g = ks * 4 + q;
        xa[mi] = *(const bf16x8*)&smem[t * 128 + ((g ^ (t & 15)) * 8)];
      }
#pragma unroll
      for (int mi = 0; mi < 4; mi++)
#pragma unroll
        for (int ni = 0; ni < 4; ni++)
          acc1[mi][ni] = __builtin_amdgcn_mfma_f32_16x16x32_bf16(
              xa[mi], wf[ni][ks], acc1[mi][ni], 0, 0, 0);
    }
#pragma unroll
    for (int ni = 0; ni < 4; ni++){
      const float bb = barr[ni];
      const int j = jh * 64 + 16 * ni + r15;
      float ps = 0.f;
#pragma unroll
      for (int mi = 0; mi < 4; mi++){
        float vals[4];
#pragma unroll
        for (int r = 0; r < 4; r++) vals[r] = acc1[mi][ni][r] + bb;
        if (jh == 0){
#pragma unroll
          for (int r = 0; r < 4; r++){ vals[r] = __expf(vals[r]); ps += vals[r]; }
        }
        uint2 pk;
        pk.x = pack2bf(vals[0], vals[1]);
        pk.y = pack2bf(vals[2], vals[3]);
        int g8 = 16 * th + 4 * mi + q;
        int g8s = g8 ^ (2 * r15);
        *(uint2*)&sekv[j * 128 + g8s * 4] = pk;
      }
      if (jh == 0){
        ps += __shfl_xor(ps, 16); ps += __shfl_xor(ps, 32);
        rs[ni] += ps;
      }
    }
    __syncthreads();
    {
      bf16x8 ka[4], va[4];
      const int g8s = (8 * w + 2 * q) ^ (2 * r15);
#pragma unroll
      for (int mi2 = 0; mi2 < 4; mi2++){
        int d = 16 * mi2 + r15;
        ka[mi2] = *(const bf16x8*)&sekv[d * 128 + g8s * 4];
      }
#pragma unroll
      for (int ni2 = 0; ni2 < 4; ni2++){
        int e = 16 * ni2 + r15;
        va[ni2] = *(const bf16x8*)&sekv[(64 + e) * 128 + g8s * 4];
      }
#pragma unroll
      for (int mi2 = 0; mi2 < 4; mi2++)
#pragma unroll
        for (int ni2 = 0; ni2 < 4; ni2++)
          acc2[mi2][ni2] = __builtin_amdgcn_mfma_f32_16x16x32_bf16(
              ka[mi2], va[ni2], acc2[mi2][ni2], 0, 0, 0);
    }
    __syncthreads();
  }
  float* fb = (float*)smem;
#pragma unroll
  for (int mi2 = 0; mi2 < 4; mi2++)
#pragma unroll
    for (int ni2 = 0; ni2 < 4; ni2++)
#pragma unroll
      for (int r = 0; r < 4; r++){
        int d = 16 * mi2 + 4 * q + r, e = 16 * ni2 + r15;
        fb[w * 4096 + d * 64 + e] = acc2[mi2][ni2][r];
      }
  __syncthreads();
  {
    float* dst = pctx + ((size_t)((b * 8 + h) * 32 + chunk)) * 4096 + tid * 16;
#pragma unroll
    for (int i = 0; i < 4; i++){
      int o = tid * 16 + 4 * i;
      float4 a = *(const float4*)(fb + o);
      float4 c = *(const float4*)(fb + 4096 + o);
      float4 d = *(const float4*)(fb + 8192 + o);
      float4 e = *(const float4*)(fb + 12288 + o);
      float4 s;
      s.x = a.x + c.x + d.x + e.x; s.y = a.y + c.y + d.y + e.y;
      s.z = a.z + c.z + d.z + e.z; s.w = a.w + c.w + d.w + e.w;
      *(float4*)(dst + 4 * i) = s;
    }
  }
  if (jh == 0 && q == 0){
    float* rb = prs + ((size_t)((b * 8 + h) * 32 + chunk)) * 128 + th * 64;
#pragma unroll
    for (int ni = 0; ni < 4; ni++) rb[16 * ni + r15] = rs[ni];
  }
}

// ---------------------------------------------------------------------------
// ctxred R8: grid (32 bh, 8 slices) = 256 blocks. Each block sums its
// 512-float slice across 32 chunk-partials (float2-coalesced).
// ---------------------------------------------------------------------------
__global__ __launch_bounds__(256) void ctxred(const float* __restrict__ pctx,
    const float* __restrict__ prs, float* __restrict__ ctx,
    float* __restrict__ rowsum){
  const int bh = blockIdx.x, s = blockIdx.y, tid = threadIdx.x;
  const float2* base = (const float2*)(pctx + (size_t)bh * 32 * 4096 + s * 512) + tid;
  float2 acc = {0.f, 0.f};
#pragma unroll 4
  for (int t = 0; t < 32; t++){
    float2 v = base[t * 2048];
    acc.x += v.x; acc.y += v.y;
  }
  *((float2*)(ctx + (size_t)bh * 4096 + s * 512) + tid) = acc;
  if (s == 0 && tid < 64){
    const float* rb = prs + (size_t)bh * 32 * 128 + tid;
    float sm = 0.f;
    for (int t = 0; t < 32; t++) sm += rb[t * 128] + rb[t * 128 + 64];
    rowsum[bh * 64 + tid] = sm;
  }
}

// ---------------------------------------------------------------------------
// mker: M[c][d] = (1/rowsum[d]) * sum_e Wo[c][h*64+e] * ctx[b][h][d][e]
// stored as A-frags for qout MFMA2: f = (bh*8 + (c>>4))*2 + (d>>5).
// ---------------------------------------------------------------------------
__global__ __launch_bounds__(256) void mker(const float* __restrict__ ctx,
    const float* __restrict__ Wo, const float* __restrict__ rowsum,
    u16* __restrict__ mtf){
  __shared__ float ctxh[64][68];
  __shared__ float woht[64][132];
  const int tid = threadIdx.x;
  const int h = blockIdx.x, b = blockIdx.y;
  const int bh = b * 8 + h;
  const int e4 = tid & 15, r0 = tid >> 4;
#pragma unroll
  for (int p = 0; p < 4; p++){
    int d = r0 + p * 16;
    float4 v = *(const float4*)(ctx + ((size_t)bh * 64 + d) * 64 + 4 * e4);
    *(float4*)&ctxh[d][4 * e4] = v;
  }
#pragma unroll
  for (int p = 0; p < 8; p++){
    int c = r0 + p * 16;
    float4 v = *(const float4*)(Wo + (size_t)c * 512 + h * 64 + 4 * e4);
    woht[4 * e4 + 0][c] = v.x; woht[4 * e4 + 1][c] = v.y;
    woht[4 * e4 + 2][c] = v.z; woht[4 * e4 + 3][c] = v.w;
  }
  __syncthreads();
  const int cg = tid & 3, d = tid >> 2;
  const float inv = 1.f / rowsum[bh * 64 + d];
  float acc[32];
#pragma unroll
  for (int cc = 0; cc < 32; cc++) acc[cc] = 0.f;
  for (int e = 0; e < 64; e++){
    float cv = ctxh[d][e];
#pragma unroll
    for (int cc = 0; cc < 32; cc++) acc[cc] += cv * woht[e][cg + 4 * cc];
  }
  const int ks = d >> 5, lq = ((d >> 3) & 3) << 4, el = d & 7;
#pragma unroll
  for (int cc = 0; cc < 32; cc++){
    int c = cg + 4 * cc;
    mtf[((size_t)(bh * 8 + (c >> 4)) * 2 + ks) * 512 + ((c & 15) | lq) * 8 + el]
        = f2bf(inv * acc[cc]);
  }
}

// ---------------------------------------------------------------------------
// qout R8: 64-token tiles -> 1024 blocks (4/CU). Wave owns 16 tokens. LDS:
// smX 16 KiB + smP 8 KiB = 24 KiB. Same frag layouts; one barrier total.
// ---------------------------------------------------------------------------
__global__ __launch_bounds__(256, 2) void qout(const u16* __restrict__ xt,
    const u16* __restrict__ wqf, const float* __restrict__ bqs,
    const u16* __restrict__ mtf, const float* __restrict__ bo,
    float* __restrict__ out){
  __shared__ u16 smX[64 * 128];   // [64t][128k] swizzled
  __shared__ u16 smP[4][16 * 64]; // per-wave p[16t][64d]
  const int tid = threadIdx.x;
  const int tt = blockIdx.x, b = blockIdx.y;
  const int w = tid >> 6, l = tid & 63, r15 = l & 15, q = l >> 4;
  const int t0 = tt * 64;
  const int m7 = 2 * (r15 & 7);

  { // stage smX: thread stages 64 B of row tid>>2
    const int row = tid >> 2, gq = tid & 3;
    const u16* src = xt + (size_t)(b * N_ + t0 + row) * 128;
#pragma unroll
    for (int p = 0; p < 4; p++){
      int g = gq * 4 + p;
      *(uint4*)&smX[row * 128 + ((g ^ (row & 15)) * 8)] =
          *(const uint4*)(src + g * 8);
    }
  }
  __syncthreads();   // the only barrier

  u16* sp = smP[w];
  f32x4 acc3[8] = {};
  for (int h = 0; h < 8; h++){
    float bq_[4][4];
#pragma unroll
    for (int mi = 0; mi < 4; mi++)
#pragma unroll
      for (int r = 0; r < 4; r++)
        bq_[mi][r] = bqs[h * 64 + 16 * mi + 4 * q + r];
    // MFMA1: D[d 64][t 16], K=128; A = wq frags (global), B = x (LDS)
    f32x4 acc1[4] = {};
#pragma unroll
    for (int ks = 0; ks < 4; ks++){
      bf16x8 wqv[4];
#pragma unroll
      for (int mi = 0; mi < 4; mi++)
        wqv[mi] = *(const bf16x8*)(wqf +
            (size_t)((h * 4 + mi) * 4 + ks) * 512 + l * 8);
      const int tl = w * 16 + r15, g = ks * 4 + q;
      bf16x8 xb = *(const bf16x8*)&smX[tl * 128 + ((g ^ (tl & 15)) * 8)];
#pragma unroll
      for (int mi = 0; mi < 4; mi++)
        acc1[mi] = __builtin_amdgcn_mfma_f32_16x16x32_bf16(
            wqv[mi], xb, acc1[mi], 0, 0, 0);
    }
    // exp + in-wave colsum + normalized p store (wave-private)
    {
      float ps = 0.f;
#pragma unroll
      for (int mi = 0; mi < 4; mi++)
#pragma unroll
        for (int r = 0; r < 4; r++){
          float e = __expf(acc1[mi][r] + bq_[mi][r]);
          acc1[mi][r] = e; ps += e;
        }
      ps += __shfl_xor(ps, 16); ps += __shfl_xor(ps, 32);
      const float ci = 1.f / ps;
#pragma unroll
      for (int mi = 0; mi < 4; mi++){
        uint2 pk;
        pk.x = pack2bf(acc1[mi][0] * ci, acc1[mi][1] * ci);
        pk.y = pack2bf(acc1[mi][2] * ci, acc1[mi][3] * ci);
        int g8s = (4 * mi + q) ^ m7;
        *(uint2*)&sp[r15 * 64 + g8s * 4] = pk;
      }
    }
    // MFMA2: out[c 128][t 16] += M_h · p, K=64
#pragma unroll
    for (int ks2 = 0; ks2 < 2; ks2++){
      const int g8s = (8 * ks2 + 2 * q) ^ m7;
      bf16x8 pb = *(const bf16x8*)&sp[r15 * 64 + g8s * 4];
#pragma unroll
      for (int half = 0; half < 2; half++){
        bf16x8 mf[4];
#pragma unroll
        for (int mm = 0; mm < 4; mm++)
          mf[mm] = *(const bf16x8*)(mtf +
              ((size_t)((b * 8 + h) * 8 + half * 4 + mm) * 2 + ks2) * 512 + l * 8);
#pragma unroll
        for (int mm = 0; mm < 4; mm++)
          acc3[half * 4 + mm] = __builtin_amdgcn_mfma_f32_16x16x32_bf16(
              mf[mm], pb, acc3[half * 4 + mm], 0, 0, 0);
      }
    }
  }
#pragma unroll
  for (int mi = 0; mi < 8; mi++)
#pragma unroll
    for (int r = 0; r < 4; r++){
      int c = 16 * mi + 4 * q + r;
      float bb = bo[c];
      int t = t0 + w * 16 + r15;
      out[(size_t)(b * 128 + c) * N_ + t] = acc3[mi][r] + bb;
    }
}

// ---------------------------------------------------------------------------
extern "C" void kernel_launch(void* const* d_in, const int* in_sizes, int n_in,
                              void* d_out, int out_size, void* d_ws, size_t ws_size,
                              hipStream_t stream){
  const float* x  = (const float*)d_in[0];
  const float* Wq = (const float*)d_in[1];
  const float* bq = (const float*)d_in[2];
  const float* Wk = (const float*)d_in[3];
  const float* bk = (const float*)d_in[4];
  const float* Wv = (const float*)d_in[5];
  const float* bv = (const float*)d_in[6];
  const float* Wo = (const float*)d_in[7];
  const float* bo = (const float*)d_in[8];
  float* out = (float*)d_out;

  char* ws = (char*)d_ws;
  u16*   xt     = (u16*)ws;                         // 16 MiB
  u16*   wkvf   = (u16*)(ws + 16777216);            // 256 KiB
  u16*   wqf    = (u16*)(ws + 17039360);            // 128 KiB
  u16*   mtf    = (u16*)(ws + 17170432);            // 512 KiB
  float* bkv    = (float*)(ws + 17694720);          // 4 KiB
  float* bqs    = (float*)(ws + 17698816);          // 2 KiB
  float* rowsum = (float*)(ws + 17700864);          // 8 KiB
  float* ctx    = (float*)(ws + 17709056);          // 512 KiB
  float* pctx   = (float*)(ws + 18233344);          // 16 MiB
  float* prs    = (float*)(ws + 35010560);          // 512 KiB

  prep <<<96, 256, 0, stream>>>(Wq, bq, Wk, bk, Wv, bv, wkvf, wqf, bkv, bqs);
  convx<<<dim3(256, 4), 256, 0, stream>>>(x, xt);
  kvctx<<<dim3(32, 8, 4), 256, 0, stream>>>(xt, wkvf, bkv, pctx, prs);
  ctxred<<<dim3(32, 8), 256, 0, stream>>>(pctx, prs, ctx, rowsum);
  mker <<<dim3(8, 4), 256, 0, stream>>>(ctx, Wo, rowsum, mtf);
  qout <<<dim3(256, 4), 256, 0, stream>>>(xt, wqf, bqs, mtf, bo, out);
}